// Round 9
// baseline (3360.450 us; speedup 1.0000x reference)
//
#include <hip/hip_runtime.h>
#include <cstdio>

typedef __bf16 bf16x8 __attribute__((ext_vector_type(8)));
typedef float f32x4 __attribute__((ext_vector_type(4)));

#define DEV __device__ __forceinline__

DEV short f2bf(float f) {
    unsigned u = __builtin_bit_cast(unsigned, f);
    u += 0x7fffu + ((u >> 16) & 1u);   // RNE
    return (short)(u >> 16);
}
DEV float bf2f(short s) {
    unsigned u = ((unsigned)(unsigned short)s) << 16;
    return __builtin_bit_cast(float, u);
}
DEV float sigmoidf_(float x) { return 1.0f / (1.0f + __expf(-x)); }
DEV float tanhf_(float x) { float e = __expf(2.0f * x); return 1.0f - 2.0f / (e + 1.0f); }

DEV void gload_lds16(const void* g, void* l) {
    __builtin_amdgcn_global_load_lds(
        (__attribute__((address_space(1))) void*)(g),
        (__attribute__((address_space(3))) void*)(l), 16, 0, 0);
}

DEV f32x4 mfma16(bf16x8 a, bf16x8 b, f32x4 c) {
    return __builtin_amdgcn_mfma_f32_16x16x32_bf16(a, b, c, 0, 0, 0);
}

// ---------------- f32 -> bf16 convert ----------------
__global__ void f2bf_vec(const float* __restrict__ in, short* __restrict__ out, int n4) {
    int i = blockIdx.x * 256 + threadIdx.x;
    if (i >= n4) return;
    float4 v = reinterpret_cast<const float4*>(in)[i];
    short4 o;
    o.x = f2bf(v.x); o.y = f2bf(v.y); o.z = f2bf(v.z); o.w = f2bf(v.w);
    reinterpret_cast<short4*>(out)[i] = o;
}

// ---------------- pack Wh [1536][512] f32 into MFMA B-fragment order ----------------
__global__ void pack_wh(const float* __restrict__ Wh, short* __restrict__ Wp) {
    int tile = blockIdx.x, kk = blockIdx.y, l = threadIdx.x;  // 96 x 16, 64 thr
    int n = tile * 16 + (l & 15);
    int k0 = kk * 32 + (l >> 4) * 8;
    const float* src = Wh + (size_t)n * 512 + k0;
    short o[8];
#pragma unroll
    for (int e = 0; e < 8; e++) o[e] = f2bf(src[e]);
    *(int4*)(Wp + ((size_t)(tile * 16 + kk) * 64 + l) * 8) = *(int4*)o;
}

// ---------------- GEMM: C[m,n] = sum_k A[m,k] * W[n,k] + bias[n] ----------------
enum { M_XW1 = 0, M_UAW = 1, M_UAS = 2, M_XW2 = 3 };

template<int MODE>
__global__ __launch_bounds__(256) void gemm_bt(
    const short* __restrict__ Abase, const short* __restrict__ A2,
    const int* __restrict__ tok0, const int* __restrict__ tok1,
    const short* __restrict__ W, const float* __restrict__ bias,
    short* __restrict__ C, int M, int N, int K)
{
    __shared__ short Als[128 * 64];
    __shared__ short Bls[128 * 64];
    int tid = threadIdx.x;
    int m0 = blockIdx.y * 128, n0 = blockIdx.x * 128;
    int kc = (tid & 7) * 8;

    const short* arow[4];
#pragma unroll
    for (int i = 0; i < 4; i++) {
        int gm = m0 + i * 32 + (tid >> 3);
        if (MODE == M_XW1) {
            int t = gm >> 8, s = gm & 255;
            int tok = (s < 128) ? tok0[s * 256 + t] : tok1[(s - 128) * 256 + t];
            arow[i] = Abase + (size_t)tok * 512;
        } else if (MODE == M_UAW) {
            int t = gm >> 7, b = gm & 127;
            arow[i] = Abase + (size_t)tok0[b * 256 + t] * 512;
        } else if (MODE == M_UAS) {
            int t = gm >> 7, b = gm & 127;
            arow[i] = Abase + ((size_t)t * 256 + b) * 512;
        } else {
            arow[i] = Abase + (size_t)gm * 512;
        }
    }

    f32x4 acc[4][4] = {};
    int l = tid & 63, w = tid >> 6;
    int wm = (w >> 1) * 64, wn = (w & 1) * 64;

    for (int kt = 0; kt < K; kt += 64) {
#pragma unroll
        for (int i = 0; i < 4; i++) {
            const short* asrc;
            if (MODE == M_XW2) {
                int gm = m0 + i * 32 + (tid >> 3);
                const short* base = (kt < 512) ? Abase : A2;
                asrc = base + (size_t)gm * 512 + (kt & 511) + kc;
            } else {
                asrc = arow[i] + kt + kc;
            }
            gload_lds16(asrc, &Als[i * 2048 + tid * 8]);
        }
#pragma unroll
        for (int i = 0; i < 4; i++) {
            const short* bsrc = W + (size_t)(n0 + i * 32 + (tid >> 3)) * K + kt + kc;
            gload_lds16(bsrc, &Bls[i * 2048 + tid * 8]);
        }
        __syncthreads();
#pragma unroll
        for (int kk = 0; kk < 2; kk++) {
            int ko = kk * 32 + (l >> 4) * 8;
            bf16x8 af[4], bfr[4];
#pragma unroll
            for (int mi = 0; mi < 4; mi++)
                af[mi] = *(const bf16x8*)&Als[(wm + mi * 16 + (l & 15)) * 64 + ko];
#pragma unroll
            for (int ni = 0; ni < 4; ni++)
                bfr[ni] = *(const bf16x8*)&Bls[(wn + ni * 16 + (l & 15)) * 64 + ko];
#pragma unroll
            for (int mi = 0; mi < 4; mi++)
#pragma unroll
                for (int ni = 0; ni < 4; ni++)
                    acc[mi][ni] = mfma16(af[mi], bfr[ni], acc[mi][ni]);
        }
        __syncthreads();
    }
#pragma unroll
    for (int ni = 0; ni < 4; ni++) {
        int col = n0 + wn + ni * 16 + (l & 15);
        float bv = bias[col];
#pragma unroll
        for (int mi = 0; mi < 4; mi++) {
            int row0 = m0 + wm + mi * 16 + (l >> 4) * 4;
#pragma unroll
            for (int j = 0; j < 4; j++)
                C[(size_t)(row0 + j) * N + col] = f2bf(acc[mi][ni][j] + bv);
        }
    }
}

// ---------------- GRU scan v9: v7 skeleton + done-word-line sync + register own-h ----------
// Grid = (16 col-blocks of 32 cols, S/32 row-groups), 256 threads (4 waves).
// Wave w: row-tile rt=w>>1 (16 rows), col-tile ct=w&1 (16 cols), 3 gates = 48 MFMA/step.
// Wh slice (96 KB packed fragments) LDS-resident. All cross-wg h traffic uses
// AGENT-scope RELAXED atomic load/store (HW-proven path, rounds 5-7, absmax 0.0).
// Sync: per-(rg,cb) done words in ONE 64B line per rg. Writer: __syncthreads
// (drains vmcnt -> h stores acked at the coherence point) then store done=t+1.
// Reader: threads 0..15 each poll one word (16 parallel loads ~= 1 RTT/round).
// No RMW contention, no wbl2/inv anywhere.
// Own h cells (z*h term) carried in f32 registers: the gate-phase partition
// equals the consumption partition, so hp[j](t+1) == hv[j](t) of the same thread.
template<int WRITE_ALL>
__global__ __launch_bounds__(256, 1) void gru_scan9(
    const short* __restrict__ xW,   // [T][S][1536] bf16 (includes bi)
    const short* __restrict__ Wp,   // packed Wh fragments [96][16][64][8] bf16
    const float* __restrict__ bh,   // [1536]
    short* __restrict__ hb0, short* __restrict__ hb1,  // [S][512] bf16 ping-pong
    short* __restrict__ h_all,      // [T][S][512] bf16 (WRITE_ALL)
    float* __restrict__ h_final,    // [S][512] f32 (!WRITE_ALL, t==T-1)
    unsigned* __restrict__ done,    // per-rg 16 done-words, stride 32 u32 (128B)
    int S, int T)
{
    __shared__ char wl[96 * 1024];   // Wh fragments [6 lg][16 kk][64 lane][16B]

    int cb = blockIdx.x;             // col block (32 cols)
    int rg = blockIdx.y;             // row group (32 rows)
    int r0 = rg * 32;
    int tid = threadIdx.x;
    int w = tid >> 6, l = tid & 63;
    int rt = w >> 1, ct = w & 1;
    int lrow = l & 15, lq = l >> 4;
    int colg = cb * 32 + ct * 16 + lrow;
    unsigned* mydone = done + rg * 32;

    // stage Wh slice once: local gtile lg = g*2+c2 <-> global g*32 + cb*2 + c2
    for (int rr = 0; rr < 24; rr++) {
        int flat = rr * 256 + tid;               // [0, 6144) 16B chunks
        int lane = flat & 63, kk = (flat >> 6) & 15, lg = flat >> 10;
        int g = lg >> 1, c2 = lg & 1;
        gload_lds16(Wp + (((size_t)(g * 32 + cb * 2 + c2) * 16 + kk) * 64 + lane) * 8,
                    wl + flat * 16);
    }
    float bhv[3];
#pragma unroll
    for (int g = 0; g < 3; g++) bhv[g] = bh[g * 512 + colg];
    __syncthreads();   // drains Wh DMA

    float hp[4] = {};   // own h cells, carried in registers across steps

    for (int t = 0; t < T; t++) {
        // xW loads issued before the wait; land in registers during the spin
        short xrv[4], xzv[4], xnv[4];
        const short* xbase = xW + ((size_t)t * S + r0) * 1536 + colg;
#pragma unroll
        for (int j = 0; j < 4; j++) {
            const short* xp = xbase + (size_t)(rt * 16 + lq * 4 + j) * 1536;
            xrv[j] = xp[0]; xzv[j] = xp[512]; xnv[j] = xp[1024];
        }

        f32x4 acc[3] = {};
        if (t > 0) {
            const short* hprev = ((t & 1) ? hb0 : hb1) + (size_t)r0 * 512;
            // wait: 16 threads poll the 16 peer done-words in parallel
            if (tid < 16) {
                while (__hip_atomic_load(&mydone[tid], __ATOMIC_RELAXED,
                                         __HIP_MEMORY_SCOPE_AGENT) < (unsigned)t)
                    __builtin_amdgcn_s_sleep(1);
            }
            __syncthreads();
            // A fragments: coherent 8B loads (independent -> pipelined, ~1 RTT)
            bf16x8 afr[16];
            const unsigned long long* arow =
                (const unsigned long long*)(hprev + (size_t)(rt * 16 + lrow) * 512);
#pragma unroll
            for (int kk = 0; kk < 16; kk++) {
                unsigned long long lo = __hip_atomic_load(arow + kk * 8 + lq * 2,
                    __ATOMIC_RELAXED, __HIP_MEMORY_SCOPE_AGENT);
                unsigned long long hi = __hip_atomic_load(arow + kk * 8 + lq * 2 + 1,
                    __ATOMIC_RELAXED, __HIP_MEMORY_SCOPE_AGENT);
                ulonglong2 v; v.x = lo; v.y = hi;
                afr[kk] = __builtin_bit_cast(bf16x8, v);
            }
            // MFMA: 3 gates x 16 kk (B from LDS-resident Wh)
#pragma unroll
            for (int g = 0; g < 3; g++) {
                const char* bbase = wl + (size_t)((g * 2 + ct) * 16) * 1024 + l * 16;
#pragma unroll
                for (int kk = 0; kk < 16; kk++) {
                    bf16x8 bfr = *(const bf16x8*)(bbase + kk * 1024);
                    acc[g] = mfma16(afr[kk], bfr, acc[g]);
                }
            }
        }

        // gates + coherent h_new stores; publish via own done word
        short* hnew = (t & 1) ? hb1 : hb0;
        float hv[4]; short hbv[4];
#pragma unroll
        for (int j = 0; j < 4; j++) {
            float r = sigmoidf_(bf2f(xrv[j]) + bhv[0] + acc[0][j]);
            float z = sigmoidf_(bf2f(xzv[j]) + bhv[1] + acc[1][j]);
            float n = tanhf_(bf2f(xnv[j]) + r * (acc[2][j] + bhv[2]));
            hv[j] = (1.f - z) * n + z * hp[j];
            hp[j] = hv[j];                      // own cell stays in registers (f32)
            hbv[j] = f2bf(hv[j]);
            __hip_atomic_store(
                (unsigned short*)hnew + (size_t)(r0 + rt * 16 + lq * 4 + j) * 512 + colg,
                (unsigned short)hbv[j], __ATOMIC_RELAXED, __HIP_MEMORY_SCOPE_AGENT);
        }
        __syncthreads();   // per-thread vmcnt(0) drain: h stores acked before publish
        if (tid == 0)
            __hip_atomic_store(&mydone[cb], (unsigned)(t + 1),
                               __ATOMIC_RELAXED, __HIP_MEMORY_SCOPE_AGENT);
        // off-chain stores (not read by peers)
        if (WRITE_ALL) {
#pragma unroll
            for (int j = 0; j < 4; j++)
                h_all[((size_t)t * S + r0 + rt * 16 + lq * 4 + j) * 512 + colg] = hbv[j];
        } else if (t == T - 1) {
#pragma unroll
            for (int j = 0; j < 4; j++)
                h_final[(size_t)(r0 + rt * 16 + lq * 4 + j) * 512 + colg] = hv[j];
        }
    }
}

// ---------------- per-(b) sums: u_all_sum ----------------
__global__ void embed_sum_k(const short* __restrict__ ebf, const int* __restrict__ tok,
                            float* __restrict__ out) {
    int b = blockIdx.x, d = threadIdx.x;
    float a0 = 0.f, a1 = 0.f;
    for (int t = 0; t < 256; t++) {
        const short* row = ebf + (size_t)tok[b * 256 + t] * 512;
        a0 += bf2f(row[d]); a1 += bf2f(row[d + 256]);
    }
    out[b * 512 + d] = a0; out[b * 512 + d + 256] = a1;
}
__global__ void hall_sum_k(const short* __restrict__ h_all, float* __restrict__ out) {
    int b = blockIdx.x, d = threadIdx.x;
    float a0 = 0.f, a1 = 0.f;
    for (int t = 0; t < 256; t++) {
        const short* row = h_all + ((size_t)t * 256 + b) * 512;
        a0 += bf2f(row[d]); a1 += bf2f(row[d + 256]);
    }
    out[b * 512 + d] = a0; out[b * 512 + d + 256] = a1;
}

// ---------------- dual attention combine (one wave per (t,b)) ----------------
template<int WORD>
__global__ __launch_bounds__(256) void attn_combine(
    const short* __restrict__ uA, const short* __restrict__ rsrc,
    const int* __restrict__ rtok, const float* __restrict__ usum,
    const float* __restrict__ Wv, short* __restrict__ ctx)
{
    int l = threadIdx.x & 63, w = threadIdx.x >> 6;
    int m = blockIdx.x * 4 + w;
    int t = m >> 7, b = m & 127;
    const short* rrow;
    if (WORD) rrow = rsrc + (size_t)rtok[b * 256 + t] * 512;
    else      rrow = rsrc + ((size_t)t * 256 + 128 + b) * 512;
    const short* urow = uA + (size_t)m * 512;
    int d0 = l * 8;
    short ru[8], uu[8];
    *(int4*)ru = *(const int4*)(rrow + d0);
    *(int4*)uu = *(const int4*)(urow + d0);
    float rv[8], dot = 0.f;
#pragma unroll
    for (int i = 0; i < 8; i++) { rv[i] = bf2f(ru[i]); dot += rv[i] * bf2f(uu[i]); }
#pragma unroll
    for (int off = 32; off >= 1; off >>= 1) dot += __shfl_xor(dot, off);
    float tw = tanhf_(dot);
    float e[8], se = 0.f;
#pragma unroll
    for (int i = 0; i < 8; i++) { e[i] = __expf(tw * Wv[d0 + i]); se += e[i]; }
#pragma unroll
    for (int off = 32; off >= 1; off >>= 1) se += __shfl_xor(se, off);
    float inv = 1.f / se;
    short ov[8];
#pragma unroll
    for (int i = 0; i < 8; i++) ov[i] = f2bf(e[i] * inv * usum[b * 512 + d0 + i] * rv[i]);
    *(int4*)(ctx + (size_t)m * 512 + d0) = *(int4*)ov;
}

// ---------------- final classifier + softmax ----------------
__global__ void final_head_k(const float* __restrict__ h2, const float* __restrict__ Wf,
                             const float* __restrict__ bfv, float* __restrict__ out) {
    int b = blockIdx.x, l = threadIdx.x;  // 64 threads
    float d0 = 0.f, d1 = 0.f;
    for (int k = l; k < 512; k += 64) {
        float h = h2[b * 512 + k];
        d0 += h * Wf[k];
        d1 += h * Wf[512 + k];
    }
#pragma unroll
    for (int off = 32; off >= 1; off >>= 1) { d0 += __shfl_xor(d0, off); d1 += __shfl_xor(d1, off); }
    if (l == 0) {
        float l0 = d0 + bfv[0], l1 = d1 + bfv[1];
        float mx = fmaxf(l0, l1);
        float e0 = __expf(l0 - mx), e1 = __expf(l1 - mx);
        float s = e0 + e1;
        out[b * 2] = e0 / s; out[b * 2 + 1] = e1 / s;
    }
}

extern "C" void kernel_launch(void* const* d_in, const int* in_sizes, int n_in,
                              void* d_out, int out_size, void* d_ws, size_t ws_size,
                              hipStream_t stream)
{
    const int* ask    = (const int*)d_in[0];
    const int* answer = (const int*)d_in[1];
    const int* askkw  = (const int*)d_in[2];
    const int* anskw  = (const int*)d_in[3];
    const float* embed = (const float*)d_in[4];
    const float* Wi1 = (const float*)d_in[5];
    const float* Wh1 = (const float*)d_in[6];
    const float* bi1 = (const float*)d_in[7];
    const float* bh1 = (const float*)d_in[8];
    const float* Aw  = (const float*)d_in[9];
    const float* bw  = (const float*)d_in[10];
    const float* Ww  = (const float*)d_in[11];
    const float* As  = (const float*)d_in[12];
    const float* bs  = (const float*)d_in[13];
    const float* Ws  = (const float*)d_in[14];
    const float* Wi2 = (const float*)d_in[15];
    const float* Wh2 = (const float*)d_in[16];
    const float* bi2 = (const float*)d_in[17];
    const float* bh2 = (const float*)d_in[18];
    const float* Wf  = (const float*)d_in[19];
    const float* bfv = (const float*)d_in[20];

    char* ws = (char*)d_ws;
    size_t off = 0;
    auto alloc = [&](size_t bytes) -> void* {
        void* p = (void*)(ws + off);
        off += (bytes + 255) & ~(size_t)255;
        return p;
    };
    short* embed_bf = (short*)alloc(50000ULL * 512 * 2);
    short* Wi1b = (short*)alloc(1536 * 512 * 2);
    short* Wp1  = (short*)alloc(1536 * 512 * 2);   // packed Wh1 fragments
    short* Awb  = (short*)alloc(512 * 512 * 2);
    short* Asb  = (short*)alloc(512 * 512 * 2);
    short* Wi2b = (short*)alloc(1536 * 1024 * 2);
    short* Wp2  = (short*)alloc(1536 * 512 * 2);   // packed Wh2 fragments
    char* X = (char*)alloc(201326592ULL);            // xW1 region, reused after GRU1
    short* xW1  = (short*)X;                         // [256][256][1536] bf16
    short* uA   = (short*)X;                         // [32768][512] bf16 (after GRU1)
    short* ctxW = (short*)(X + 33554432);            // [256][128][512] bf16
    short* ctxS = (short*)(X + 67108864);            // [256][128][512] bf16
    short* xW2  = (short*)(X + 100663296);           // [256][128][1536] bf16
    short* h_all = (short*)alloc(256ULL * 256 * 512 * 2);  // [t][s][512] bf16
    short* hb0 = (short*)alloc(256 * 512 * 2);
    short* hb1 = (short*)alloc(256 * 512 * 2);
    float* usumW = (float*)alloc(128 * 512 * 4);
    float* usumS = (float*)alloc(128 * 512 * 4);
    float* h2f   = (float*)alloc(128 * 512 * 4);
    unsigned* done1 = (unsigned*)alloc(8 * 32 * 4);  // GRU1: 8 rgs x 16 done words (128B apart)
    unsigned* done2 = (unsigned*)alloc(4 * 32 * 4);  // GRU2: 4 rgs

    if (off > ws_size) {
        fprintf(stderr, "kernel_launch: workspace too small: need %zu have %zu\n", off, ws_size);
        return;
    }

    // zero done lines (in-graph, every replay)
    hipMemsetAsync(done1, 0, 8 * 32 * 4, stream);
    hipMemsetAsync(done2, 0, 4 * 32 * 4, stream);

    auto cv = [&](const float* src, short* dst, int n) {
        int n4 = n / 4;
        f2bf_vec<<<(n4 + 255) / 256, 256, 0, stream>>>(src, dst, n4);
    };
    cv(embed, embed_bf, 50000 * 512);
    cv(Wi1, Wi1b, 1536 * 512);
    cv(Aw, Awb, 512 * 512);
    cv(As, Asb, 512 * 512);
    cv(Wi2, Wi2b, 1536 * 1024);
    pack_wh<<<dim3(96, 16), 64, 0, stream>>>(Wh1, Wp1);
    pack_wh<<<dim3(96, 16), 64, 0, stream>>>(Wh2, Wp2);

    // xW1 = gathered embeds @ Wi1^T + bi1, rows m = t*256 + s  (s<128: ask, else answer)
    gemm_bt<M_XW1><<<dim3(12, 512), 256, 0, stream>>>(
        embed_bf, nullptr, ask, answer, Wi1b, bi1, xW1, 65536, 1536, 512);

    // GRU1 over ask+ans combined (S=256): 16 col-wgs x 8 row-groups
    {
        const short* xWa = xW1; const short* Wpa = Wp1; const float* bha = bh1;
        short* a0 = hb0; short* a1 = hb1; short* ha = h_all; float* hf = h2f;
        unsigned* dp = done1; int S = 256, T = 256;
        void* args[] = { (void*)&xWa, (void*)&Wpa, (void*)&bha, (void*)&a0, (void*)&a1,
                         (void*)&ha, (void*)&hf, (void*)&dp, (void*)&S, (void*)&T };
        hipError_t e = hipLaunchCooperativeKernel(
            reinterpret_cast<void*>(&gru_scan9<1>), dim3(16, 8), dim3(256), args, 0, stream);
        if (e != hipSuccess)   // fallback: plain launch (128 wgs, 1/CU -> co-resident)
            gru_scan9<1><<<dim3(16, 8), 256, 0, stream>>>(xWa, Wpa, bha, a0, a1, ha, hf, dp, S, T);
    }

    // word attention
    embed_sum_k<<<128, 256, 0, stream>>>(embed_bf, askkw, usumW);
    gemm_bt<M_UAW><<<dim3(4, 256), 256, 0, stream>>>(
        embed_bf, nullptr, askkw, nullptr, Awb, bw, uA, 32768, 512, 512);
    attn_combine<1><<<8192, 256, 0, stream>>>(uA, embed_bf, anskw, usumW, Ww, ctxW);

    // seq attention
    hall_sum_k<<<128, 256, 0, stream>>>(h_all, usumS);
    gemm_bt<M_UAS><<<dim3(4, 256), 256, 0, stream>>>(
        h_all, nullptr, nullptr, nullptr, Asb, bs, uA, 32768, 512, 512);
    attn_combine<0><<<8192, 256, 0, stream>>>(uA, h_all, nullptr, usumS, Ws, ctxS);

    // xW2 = [ctxW | ctxS] @ Wi2^T + bi2, rows m = t*128 + b
    gemm_bt<M_XW2><<<dim3(12, 256), 256, 0, stream>>>(
        ctxW, ctxS, nullptr, nullptr, Wi2b, bi2, xW2, 32768, 1536, 1024);

    // GRU2 (S=128): 16 col-wgs x 4 row-groups, keep only final hidden state
    {
        const short* xWa = xW2; const short* Wpa = Wp2; const float* bha = bh2;
        short* a0 = hb0; short* a1 = hb1; short* ha = nullptr; float* hf = h2f;
        unsigned* dp = done2; int S = 128, T = 256;
        void* args[] = { (void*)&xWa, (void*)&Wpa, (void*)&bha, (void*)&a0, (void*)&a1,
                         (void*)&ha, (void*)&hf, (void*)&dp, (void*)&S, (void*)&T };
        hipError_t e = hipLaunchCooperativeKernel(
            reinterpret_cast<void*>(&gru_scan9<0>), dim3(16, 4), dim3(256), args, 0, stream);
        if (e != hipSuccess)
            gru_scan9<0><<<dim3(16, 4), 256, 0, stream>>>(xWa, Wpa, bha, a0, a1, ha, hf, dp, S, T);
    }

    final_head_k<<<128, 64, 0, stream>>>(h2f, Wf, bfv, (float*)d_out);
}

// Round 10
// 2227.328 us; speedup vs baseline: 1.5087x; 1.5087x over previous
//
#include <hip/hip_runtime.h>
#include <cstdio>

typedef __bf16 bf16x8 __attribute__((ext_vector_type(8)));
typedef float f32x4 __attribute__((ext_vector_type(4)));

#define DEV __device__ __forceinline__

DEV short f2bf(float f) {
    unsigned u = __builtin_bit_cast(unsigned, f);
    u += 0x7fffu + ((u >> 16) & 1u);   // RNE
    return (short)(u >> 16);
}
DEV float bf2f(short s) {
    unsigned u = ((unsigned)(unsigned short)s) << 16;
    return __builtin_bit_cast(float, u);
}
DEV float sigmoidf_(float x) { return 1.0f / (1.0f + __expf(-x)); }
DEV float tanhf_(float x) { float e = __expf(2.0f * x); return 1.0f - 2.0f / (e + 1.0f); }

DEV void gload_lds16(const void* g, void* l) {
    __builtin_amdgcn_global_load_lds(
        (__attribute__((address_space(1))) void*)(g),
        (__attribute__((address_space(3))) void*)(l), 16, 0, 0);
}

DEV f32x4 mfma16(bf16x8 a, bf16x8 b, f32x4 c) {
    return __builtin_amdgcn_mfma_f32_16x16x32_bf16(a, b, c, 0, 0, 0);
}

// ---------------- f32 -> bf16 convert ----------------
__global__ void f2bf_vec(const float* __restrict__ in, short* __restrict__ out, int n4) {
    int i = blockIdx.x * 256 + threadIdx.x;
    if (i >= n4) return;
    float4 v = reinterpret_cast<const float4*>(in)[i];
    short4 o;
    o.x = f2bf(v.x); o.y = f2bf(v.y); o.z = f2bf(v.z); o.w = f2bf(v.w);
    reinterpret_cast<short4*>(out)[i] = o;
}

// ---------------- pack Wh [1536][512] f32 into MFMA B-fragment order ----------------
__global__ void pack_wh(const float* __restrict__ Wh, short* __restrict__ Wp) {
    int tile = blockIdx.x, kk = blockIdx.y, l = threadIdx.x;  // 96 x 16, 64 thr
    int n = tile * 16 + (l & 15);
    int k0 = kk * 32 + (l >> 4) * 8;
    const float* src = Wh + (size_t)n * 512 + k0;
    short o[8];
#pragma unroll
    for (int e = 0; e < 8; e++) o[e] = f2bf(src[e]);
    *(int4*)(Wp + ((size_t)(tile * 16 + kk) * 64 + l) * 8) = *(int4*)o;
}

// ---------------- GEMM: C[m,n] = sum_k A[m,k] * W[n,k] + bias[n] ----------------
enum { M_XW1 = 0, M_UAW = 1, M_UAS = 2, M_XW2 = 3 };

template<int MODE>
__global__ __launch_bounds__(256) void gemm_bt(
    const short* __restrict__ Abase, const short* __restrict__ A2,
    const int* __restrict__ tok0, const int* __restrict__ tok1,
    const short* __restrict__ W, const float* __restrict__ bias,
    short* __restrict__ C, int M, int N, int K)
{
    __shared__ short Als[128 * 64];
    __shared__ short Bls[128 * 64];
    int tid = threadIdx.x;
    int m0 = blockIdx.y * 128, n0 = blockIdx.x * 128;
    int kc = (tid & 7) * 8;

    const short* arow[4];
#pragma unroll
    for (int i = 0; i < 4; i++) {
        int gm = m0 + i * 32 + (tid >> 3);
        if (MODE == M_XW1) {
            int t = gm >> 8, s = gm & 255;
            int tok = (s < 128) ? tok0[s * 256 + t] : tok1[(s - 128) * 256 + t];
            arow[i] = Abase + (size_t)tok * 512;
        } else if (MODE == M_UAW) {
            int t = gm >> 7, b = gm & 127;
            arow[i] = Abase + (size_t)tok0[b * 256 + t] * 512;
        } else if (MODE == M_UAS) {
            int t = gm >> 7, b = gm & 127;
            arow[i] = Abase + ((size_t)t * 256 + b) * 512;
        } else {
            arow[i] = Abase + (size_t)gm * 512;
        }
    }

    f32x4 acc[4][4] = {};
    int l = tid & 63, w = tid >> 6;
    int wm = (w >> 1) * 64, wn = (w & 1) * 64;

    for (int kt = 0; kt < K; kt += 64) {
#pragma unroll
        for (int i = 0; i < 4; i++) {
            const short* asrc;
            if (MODE == M_XW2) {
                int gm = m0 + i * 32 + (tid >> 3);
                const short* base = (kt < 512) ? Abase : A2;
                asrc = base + (size_t)gm * 512 + (kt & 511) + kc;
            } else {
                asrc = arow[i] + kt + kc;
            }
            gload_lds16(asrc, &Als[i * 2048 + tid * 8]);
        }
#pragma unroll
        for (int i = 0; i < 4; i++) {
            const short* bsrc = W + (size_t)(n0 + i * 32 + (tid >> 3)) * K + kt + kc;
            gload_lds16(bsrc, &Bls[i * 2048 + tid * 8]);
        }
        __syncthreads();
#pragma unroll
        for (int kk = 0; kk < 2; kk++) {
            int ko = kk * 32 + (l >> 4) * 8;
            bf16x8 af[4], bfr[4];
#pragma unroll
            for (int mi = 0; mi < 4; mi++)
                af[mi] = *(const bf16x8*)&Als[(wm + mi * 16 + (l & 15)) * 64 + ko];
#pragma unroll
            for (int ni = 0; ni < 4; ni++)
                bfr[ni] = *(const bf16x8*)&Bls[(wn + ni * 16 + (l & 15)) * 64 + ko];
#pragma unroll
            for (int mi = 0; mi < 4; mi++)
#pragma unroll
                for (int ni = 0; ni < 4; ni++)
                    acc[mi][ni] = mfma16(af[mi], bfr[ni], acc[mi][ni]);
        }
        __syncthreads();
    }
#pragma unroll
    for (int ni = 0; ni < 4; ni++) {
        int col = n0 + wn + ni * 16 + (l & 15);
        float bv = bias[col];
#pragma unroll
        for (int mi = 0; mi < 4; mi++) {
            int row0 = m0 + wm + mi * 16 + (l >> 4) * 4;
#pragma unroll
            for (int j = 0; j < 4; j++)
                C[(size_t)(row0 + j) * N + col] = f2bf(acc[mi][ni][j] + bv);
        }
    }
}

// ---------------- GRU scan v10: coalesced coherent exchange via LDS redistribution ------
// Grid = (16 col-blocks of 32 cols, S/32 row-groups), 256 threads (4 waves).
// Wave w: row-tile rt=w>>1 (16 rows), col-tile ct=w&1 (16 cols), 3 gates = 48 MFMA/step.
// Wh slice (96 KB packed fragments) LDS-resident. Coherence mechanism (HW-proven
// rounds 5-9, absmax 0.0): AGENT-scope RELAXED atomic load/store + done-word sync.
// New: all coherent traffic is lane-CONTIGUOUS (64B-coalesced), redistributed via LDS:
//  - read: 16x 8B atomic loads/thread at tid*8+k*2048 (slab 32KB, 512 txns/wg vs 8192)
//    -> regs -> ds_write (XOR-swizzled) -> afr via ds_read_b128 (~2-way, free)
//  - write: gates -> 2KB LDS tile -> one 8B atomic store/thread (32 txns/wg vs 1024)
// Own h cells carried in f32 registers across steps.
template<int WRITE_ALL>
__global__ __launch_bounds__(256, 1) void gru_scan10(
    const short* __restrict__ xW,   // [T][S][1536] bf16 (includes bi)
    const short* __restrict__ Wp,   // packed Wh fragments [96][16][64][8] bf16
    const float* __restrict__ bh,   // [1536]
    short* __restrict__ hb0, short* __restrict__ hb1,  // [S][512] bf16 ping-pong
    short* __restrict__ h_all,      // [T][S][512] bf16 (WRITE_ALL)
    float* __restrict__ h_final,    // [S][512] f32 (!WRITE_ALL, t==T-1)
    unsigned* __restrict__ done,    // per-rg 16 done-words, stride 32 u32 (128B)
    int S, int T)
{
    __shared__ char wl[96 * 1024];   // Wh fragments [6 lg][16 kk][64 lane][16B]
    __shared__ char sl[32 * 1024];   // h slab [32 rows][1024B], XOR-swizzled
    __shared__ char ho[2048];        // h out tile [32 rows][32 cols] bf16

    int cb = blockIdx.x;             // col block (32 cols)
    int rg = blockIdx.y;             // row group (32 rows)
    int r0 = rg * 32;
    int tid = threadIdx.x;
    int w = tid >> 6, l = tid & 63;
    int rt = w >> 1, ct = w & 1;
    int lrow = l & 15, lq = l >> 4;
    int colg = cb * 32 + ct * 16 + lrow;
    unsigned* mydone = done + rg * 32;

    // stage Wh slice once: local gtile lg = g*2+c2 <-> global g*32 + cb*2 + c2
    for (int rr = 0; rr < 24; rr++) {
        int flat = rr * 256 + tid;               // [0, 6144) 16B chunks
        int lane = flat & 63, kk = (flat >> 6) & 15, lg = flat >> 10;
        int g = lg >> 1, c2 = lg & 1;
        gload_lds16(Wp + (((size_t)(g * 32 + cb * 2 + c2) * 16 + kk) * 64 + lane) * 8,
                    wl + flat * 16);
    }
    float bhv[3];
#pragma unroll
    for (int g = 0; g < 3; g++) bhv[g] = bh[g * 512 + colg];
    __syncthreads();   // drains Wh DMA

    float hp[4] = {};   // own h cells, carried in registers across steps

    for (int t = 0; t < T; t++) {
        // xW loads issued before the wait; land in registers during the spin
        short xrv[4], xzv[4], xnv[4];
        const short* xbase = xW + ((size_t)t * S + r0) * 1536 + colg;
#pragma unroll
        for (int j = 0; j < 4; j++) {
            const short* xp = xbase + (size_t)(rt * 16 + lq * 4 + j) * 1536;
            xrv[j] = xp[0]; xzv[j] = xp[512]; xnv[j] = xp[1024];
        }

        f32x4 acc[3] = {};
        if (t > 0) {
            const short* hprev = ((t & 1) ? hb0 : hb1) + (size_t)r0 * 512;
            // wait: 16 threads poll the 16 peer done-words in parallel
            if (tid < 16) {
                while (__hip_atomic_load(&mydone[tid], __ATOMIC_RELAXED,
                                         __HIP_MEMORY_SCOPE_AGENT) < (unsigned)t)
                    __builtin_amdgcn_s_sleep(1);
            }
            __syncthreads();
            // cooperative coalesced coherent slab load: 32 KB, 64B-coalesced
            unsigned long long v[16];
            const unsigned long long* sp = (const unsigned long long*)hprev;
#pragma unroll
            for (int k = 0; k < 16; k++)
                v[k] = __hip_atomic_load(sp + k * 256 + tid,
                                         __ATOMIC_RELAXED, __HIP_MEMORY_SCOPE_AGENT);
#pragma unroll
            for (int k = 0; k < 16; k++) {
                int off = (k * 256 + tid) * 8;
                int row = off >> 10, colb = off & 1023;
                *(unsigned long long*)(sl + row * 1024 + (colb ^ ((row & 7) << 4))) = v[k];
            }
            __syncthreads();
            // A fragments from swizzled LDS slab
            bf16x8 afr[16];
            int ar = rt * 16 + lrow;
#pragma unroll
            for (int kk = 0; kk < 16; kk++) {
                int colb = kk * 64 + lq * 16;
                afr[kk] = *(const bf16x8*)(sl + ar * 1024 + (colb ^ ((ar & 7) << 4)));
            }
            // MFMA: 3 gates x 16 kk (B from LDS-resident Wh)
#pragma unroll
            for (int g = 0; g < 3; g++) {
                const char* bbase = wl + (size_t)((g * 2 + ct) * 16) * 1024 + l * 16;
#pragma unroll
                for (int kk = 0; kk < 16; kk++) {
                    bf16x8 bfr = *(const bf16x8*)(bbase + kk * 1024);
                    acc[g] = mfma16(afr[kk], bfr, acc[g]);
                }
            }
        }

        // gates -> LDS out tile (own h stays in registers)
        float hv[4];
#pragma unroll
        for (int j = 0; j < 4; j++) {
            float r = sigmoidf_(bf2f(xrv[j]) + bhv[0] + acc[0][j]);
            float z = sigmoidf_(bf2f(xzv[j]) + bhv[1] + acc[1][j]);
            float n = tanhf_(bf2f(xnv[j]) + r * (acc[2][j] + bhv[2]));
            hv[j] = (1.f - z) * n + z * hp[j];
            hp[j] = hv[j];
            *(short*)(ho + (rt * 16 + lq * 4 + j) * 64 + (ct * 16 + lrow) * 2) = f2bf(hv[j]);
        }
        __syncthreads();   // out tile complete (also: slab reads done before next overwrite)
        // cooperative coalesced coherent store of the 32x32 tile (one 8B store/thread)
        {
            int row = tid >> 3, ch = tid & 7;
            unsigned long long val = *(const unsigned long long*)(ho + row * 64 + ch * 8);
            short* hnew = (t & 1) ? hb1 : hb0;
            __hip_atomic_store(
                (unsigned long long*)(hnew + (size_t)(r0 + row) * 512 + cb * 32 + ch * 4),
                val, __ATOMIC_RELAXED, __HIP_MEMORY_SCOPE_AGENT);
            if (WRITE_ALL)
                *(unsigned long long*)(h_all + ((size_t)t * S + r0 + row) * 512 + cb * 32 + ch * 4) = val;
        }
        if (!WRITE_ALL && t == T - 1) {
#pragma unroll
            for (int j = 0; j < 4; j++)
                h_final[(size_t)(r0 + rt * 16 + lq * 4 + j) * 512 + colg] = hv[j];
        }
        __syncthreads();   // per-thread vmcnt(0) drain: coherent stores acked before publish
        if (tid == 0)
            __hip_atomic_store(&mydone[cb], (unsigned)(t + 1),
                               __ATOMIC_RELAXED, __HIP_MEMORY_SCOPE_AGENT);
    }
}

// ---------------- per-(b) sums: u_all_sum ----------------
__global__ void embed_sum_k(const short* __restrict__ ebf, const int* __restrict__ tok,
                            float* __restrict__ out) {
    int b = blockIdx.x, d = threadIdx.x;
    float a0 = 0.f, a1 = 0.f;
    for (int t = 0; t < 256; t++) {
        const short* row = ebf + (size_t)tok[b * 256 + t] * 512;
        a0 += bf2f(row[d]); a1 += bf2f(row[d + 256]);
    }
    out[b * 512 + d] = a0; out[b * 512 + d + 256] = a1;
}
__global__ void hall_sum_k(const short* __restrict__ h_all, float* __restrict__ out) {
    int b = blockIdx.x, d = threadIdx.x;
    float a0 = 0.f, a1 = 0.f;
    for (int t = 0; t < 256; t++) {
        const short* row = h_all + ((size_t)t * 256 + b) * 512;
        a0 += bf2f(row[d]); a1 += bf2f(row[d + 256]);
    }
    out[b * 512 + d] = a0; out[b * 512 + d + 256] = a1;
}

// ---------------- dual attention combine (one wave per (t,b)) ----------------
template<int WORD>
__global__ __launch_bounds__(256) void attn_combine(
    const short* __restrict__ uA, const short* __restrict__ rsrc,
    const int* __restrict__ rtok, const float* __restrict__ usum,
    const float* __restrict__ Wv, short* __restrict__ ctx)
{
    int l = threadIdx.x & 63, w = threadIdx.x >> 6;
    int m = blockIdx.x * 4 + w;
    int t = m >> 7, b = m & 127;
    const short* rrow;
    if (WORD) rrow = rsrc + (size_t)rtok[b * 256 + t] * 512;
    else      rrow = rsrc + ((size_t)t * 256 + 128 + b) * 512;
    const short* urow = uA + (size_t)m * 512;
    int d0 = l * 8;
    short ru[8], uu[8];
    *(int4*)ru = *(const int4*)(rrow + d0);
    *(int4*)uu = *(const int4*)(urow + d0);
    float rv[8], dot = 0.f;
#pragma unroll
    for (int i = 0; i < 8; i++) { rv[i] = bf2f(ru[i]); dot += rv[i] * bf2f(uu[i]); }
#pragma unroll
    for (int off = 32; off >= 1; off >>= 1) dot += __shfl_xor(dot, off);
    float tw = tanhf_(dot);
    float e[8], se = 0.f;
#pragma unroll
    for (int i = 0; i < 8; i++) { e[i] = __expf(tw * Wv[d0 + i]); se += e[i]; }
#pragma unroll
    for (int off = 32; off >= 1; off >>= 1) se += __shfl_xor(se, off);
    float inv = 1.f / se;
    short ov[8];
#pragma unroll
    for (int i = 0; i < 8; i++) ov[i] = f2bf(e[i] * inv * usum[b * 512 + d0 + i] * rv[i]);
    *(int4*)(ctx + (size_t)m * 512 + d0) = *(int4*)ov;
}

// ---------------- final classifier + softmax ----------------
__global__ void final_head_k(const float* __restrict__ h2, const float* __restrict__ Wf,
                             const float* __restrict__ bfv, float* __restrict__ out) {
    int b = blockIdx.x, l = threadIdx.x;  // 64 threads
    float d0 = 0.f, d1 = 0.f;
    for (int k = l; k < 512; k += 64) {
        float h = h2[b * 512 + k];
        d0 += h * Wf[k];
        d1 += h * Wf[512 + k];
    }
#pragma unroll
    for (int off = 32; off >= 1; off >>= 1) { d0 += __shfl_xor(d0, off); d1 += __shfl_xor(d1, off); }
    if (l == 0) {
        float l0 = d0 + bfv[0], l1 = d1 + bfv[1];
        float mx = fmaxf(l0, l1);
        float e0 = __expf(l0 - mx), e1 = __expf(l1 - mx);
        float s = e0 + e1;
        out[b * 2] = e0 / s; out[b * 2 + 1] = e1 / s;
    }
}

extern "C" void kernel_launch(void* const* d_in, const int* in_sizes, int n_in,
                              void* d_out, int out_size, void* d_ws, size_t ws_size,
                              hipStream_t stream)
{
    const int* ask    = (const int*)d_in[0];
    const int* answer = (const int*)d_in[1];
    const int* askkw  = (const int*)d_in[2];
    const int* anskw  = (const int*)d_in[3];
    const float* embed = (const float*)d_in[4];
    const float* Wi1 = (const float*)d_in[5];
    const float* Wh1 = (const float*)d_in[6];
    const float* bi1 = (const float*)d_in[7];
    const float* bh1 = (const float*)d_in[8];
    const float* Aw  = (const float*)d_in[9];
    const float* bw  = (const float*)d_in[10];
    const float* Ww  = (const float*)d_in[11];
    const float* As  = (const float*)d_in[12];
    const float* bs  = (const float*)d_in[13];
    const float* Ws  = (const float*)d_in[14];
    const float* Wi2 = (const float*)d_in[15];
    const float* Wh2 = (const float*)d_in[16];
    const float* bi2 = (const float*)d_in[17];
    const float* bh2 = (const float*)d_in[18];
    const float* Wf  = (const float*)d_in[19];
    const float* bfv = (const float*)d_in[20];

    char* ws = (char*)d_ws;
    size_t off = 0;
    auto alloc = [&](size_t bytes) -> void* {
        void* p = (void*)(ws + off);
        off += (bytes + 255) & ~(size_t)255;
        return p;
    };
    short* embed_bf = (short*)alloc(50000ULL * 512 * 2);
    short* Wi1b = (short*)alloc(1536 * 512 * 2);
    short* Wp1  = (short*)alloc(1536 * 512 * 2);   // packed Wh1 fragments
    short* Awb  = (short*)alloc(512 * 512 * 2);
    short* Asb  = (short*)alloc(512 * 512 * 2);
    short* Wi2b = (short*)alloc(1536 * 1024 * 2);
    short* Wp2  = (short*)alloc(1536 * 512 * 2);   // packed Wh2 fragments
    char* X = (char*)alloc(201326592ULL);            // xW1 region, reused after GRU1
    short* xW1  = (short*)X;                         // [256][256][1536] bf16
    short* uA   = (short*)X;                         // [32768][512] bf16 (after GRU1)
    short* ctxW = (short*)(X + 33554432);            // [256][128][512] bf16
    short* ctxS = (short*)(X + 67108864);            // [256][128][512] bf16
    short* xW2  = (short*)(X + 100663296);           // [256][128][1536] bf16
    short* h_all = (short*)alloc(256ULL * 256 * 512 * 2);  // [t][s][512] bf16
    short* hb0 = (short*)alloc(256 * 512 * 2);
    short* hb1 = (short*)alloc(256 * 512 * 2);
    float* usumW = (float*)alloc(128 * 512 * 4);
    float* usumS = (float*)alloc(128 * 512 * 4);
    float* h2f   = (float*)alloc(128 * 512 * 4);
    unsigned* done1 = (unsigned*)alloc(8 * 32 * 4);  // GRU1: 8 rgs x 16 done words
    unsigned* done2 = (unsigned*)alloc(4 * 32 * 4);  // GRU2: 4 rgs

    if (off > ws_size) {
        fprintf(stderr, "kernel_launch: workspace too small: need %zu have %zu\n", off, ws_size);
        return;
    }

    // zero done lines (in-graph, every replay)
    hipMemsetAsync(done1, 0, 8 * 32 * 4, stream);
    hipMemsetAsync(done2, 0, 4 * 32 * 4, stream);

    auto cv = [&](const float* src, short* dst, int n) {
        int n4 = n / 4;
        f2bf_vec<<<(n4 + 255) / 256, 256, 0, stream>>>(src, dst, n4);
    };
    cv(embed, embed_bf, 50000 * 512);
    cv(Wi1, Wi1b, 1536 * 512);
    cv(Aw, Awb, 512 * 512);
    cv(As, Asb, 512 * 512);
    cv(Wi2, Wi2b, 1536 * 1024);
    pack_wh<<<dim3(96, 16), 64, 0, stream>>>(Wh1, Wp1);
    pack_wh<<<dim3(96, 16), 64, 0, stream>>>(Wh2, Wp2);

    // xW1 = gathered embeds @ Wi1^T + bi1, rows m = t*256 + s  (s<128: ask, else answer)
    gemm_bt<M_XW1><<<dim3(12, 512), 256, 0, stream>>>(
        embed_bf, nullptr, ask, answer, Wi1b, bi1, xW1, 65536, 1536, 512);

    // GRU1 over ask+ans combined (S=256): 16 col-wgs x 8 row-groups
    {
        const short* xWa = xW1; const short* Wpa = Wp1; const float* bha = bh1;
        short* a0 = hb0; short* a1 = hb1; short* ha = h_all; float* hf = h2f;
        unsigned* dp = done1; int S = 256, T = 256;
        void* args[] = { (void*)&xWa, (void*)&Wpa, (void*)&bha, (void*)&a0, (void*)&a1,
                         (void*)&ha, (void*)&hf, (void*)&dp, (void*)&S, (void*)&T };
        hipError_t e = hipLaunchCooperativeKernel(
            reinterpret_cast<void*>(&gru_scan10<1>), dim3(16, 8), dim3(256), args, 0, stream);
        if (e != hipSuccess)   // fallback: plain launch (128 wgs, 1/CU -> co-resident)
            gru_scan10<1><<<dim3(16, 8), 256, 0, stream>>>(xWa, Wpa, bha, a0, a1, ha, hf, dp, S, T);
    }

    // word attention
    embed_sum_k<<<128, 256, 0, stream>>>(embed_bf, askkw, usumW);
    gemm_bt<M_UAW><<<dim3(4, 256), 256, 0, stream>>>(
        embed_bf, nullptr, askkw, nullptr, Awb, bw, uA, 32768, 512, 512);
    attn_combine<1><<<8192, 256, 0, stream>>>(uA, embed_bf, anskw, usumW, Ww, ctxW);

    // seq attention
    hall_sum_k<<<128, 256, 0, stream>>>(h_all, usumS);
    gemm_bt<M_UAS><<<dim3(4, 256), 256, 0, stream>>>(
        h_all, nullptr, nullptr, nullptr, Asb, bs, uA, 32768, 512, 512);
    attn_combine<0><<<8192, 256, 0, stream>>>(uA, h_all, nullptr, usumS, Ws, ctxS);

    // xW2 = [ctxW | ctxS] @ Wi2^T + bi2, rows m = t*128 + b
    gemm_bt<M_XW2><<<dim3(12, 256), 256, 0, stream>>>(
        ctxW, ctxS, nullptr, nullptr, Wi2b, bi2, xW2, 32768, 1536, 1024);

    // GRU2 (S=128): 16 col-wgs x 4 row-groups, keep only final hidden state
    {
        const short* xWa = xW2; const short* Wpa = Wp2; const float* bha = bh2;
        short* a0 = hb0; short* a1 = hb1; short* ha = nullptr; float* hf = h2f;
        unsigned* dp = done2; int S = 128, T = 256;
        void* args[] = { (void*)&xWa, (void*)&Wpa, (void*)&bha, (void*)&a0, (void*)&a1,
                         (void*)&ha, (void*)&hf, (void*)&dp, (void*)&S, (void*)&T };
        hipError_t e = hipLaunchCooperativeKernel(
            reinterpret_cast<void*>(&gru_scan10<0>), dim3(16, 4), dim3(256), args, 0, stream);
        if (e != hipSuccess)
            gru_scan10<0><<<dim3(16, 4), 256, 0, stream>>>(xWa, Wpa, bha, a0, a1, ha, hf, dp, S, T);
    }

    final_head_k<<<128, 64, 0, stream>>>(h2f, Wf, bfv, (float*)d_out);
}

// Round 11
// 1977.353 us; speedup vs baseline: 1.6995x; 1.1264x over previous
//
#include <hip/hip_runtime.h>
#include <cstdio>

typedef __bf16 bf16x8 __attribute__((ext_vector_type(8)));
typedef float f32x4 __attribute__((ext_vector_type(4)));

#define DEV __device__ __forceinline__

DEV short f2bf(float f) {
    unsigned u = __builtin_bit_cast(unsigned, f);
    u += 0x7fffu + ((u >> 16) & 1u);   // RNE
    return (short)(u >> 16);
}
DEV float bf2f(short s) {
    unsigned u = ((unsigned)(unsigned short)s) << 16;
    return __builtin_bit_cast(float, u);
}
DEV float sigmoidf_(float x) { return 1.0f / (1.0f + __expf(-x)); }
DEV float tanhf_(float x) { float e = __expf(2.0f * x); return 1.0f - 2.0f / (e + 1.0f); }

DEV void gload_lds16(const void* g, void* l) {
    __builtin_amdgcn_global_load_lds(
        (__attribute__((address_space(1))) void*)(g),
        (__attribute__((address_space(3))) void*)(l), 16, 0, 0);
}

DEV f32x4 mfma16(bf16x8 a, bf16x8 b, f32x4 c) {
    return __builtin_amdgcn_mfma_f32_16x16x32_bf16(a, b, c, 0, 0, 0);
}

DEV unsigned ald(const unsigned* p) {
    return __hip_atomic_load(p, __ATOMIC_RELAXED, __HIP_MEMORY_SCOPE_AGENT);
}

// ---------------- f32 -> bf16 convert ----------------
__global__ void f2bf_vec(const float* __restrict__ in, short* __restrict__ out, int n4) {
    int i = blockIdx.x * 256 + threadIdx.x;
    if (i >= n4) return;
    float4 v = reinterpret_cast<const float4*>(in)[i];
    short4 o;
    o.x = f2bf(v.x); o.y = f2bf(v.y); o.z = f2bf(v.z); o.w = f2bf(v.w);
    reinterpret_cast<short4*>(out)[i] = o;
}

// ---------------- pack Wh [1536][512] f32 into MFMA B-fragment order ----------------
__global__ void pack_wh(const float* __restrict__ Wh, short* __restrict__ Wp) {
    int tile = blockIdx.x, kk = blockIdx.y, l = threadIdx.x;  // 96 x 16, 64 thr
    int n = tile * 16 + (l & 15);
    int k0 = kk * 32 + (l >> 4) * 8;
    const float* src = Wh + (size_t)n * 512 + k0;
    short o[8];
#pragma unroll
    for (int e = 0; e < 8; e++) o[e] = f2bf(src[e]);
    *(int4*)(Wp + ((size_t)(tile * 16 + kk) * 64 + l) * 8) = *(int4*)o;
}

enum { M_XW1 = 0, M_UAW = 1, M_UAS = 2, M_XW2 = 3 };

// ---------------- standalone GEMM (attention projections only) ----------------
template<int MODE>
__global__ __launch_bounds__(256) void gemm_bt(
    const short* __restrict__ Abase, const short* __restrict__ A2,
    const int* __restrict__ tok0, const int* __restrict__ tok1,
    const short* __restrict__ W, const float* __restrict__ bias,
    short* __restrict__ C, int M, int N, int K)
{
    __shared__ short Als[128 * 64];
    __shared__ short Bls[128 * 64];
    int tid = threadIdx.x;
    int m0 = blockIdx.y * 128, n0 = blockIdx.x * 128;
    int kc = (tid & 7) * 8;

    const short* arow[4];
#pragma unroll
    for (int i = 0; i < 4; i++) {
        int gm = m0 + i * 32 + (tid >> 3);
        if (MODE == M_UAW) {
            int t = gm >> 7, b = gm & 127;
            arow[i] = Abase + (size_t)tok0[b * 256 + t] * 512;
        } else {  // M_UAS
            int t = gm >> 7, b = gm & 127;
            arow[i] = Abase + ((size_t)t * 256 + b) * 512;
        }
    }

    f32x4 acc[4][4] = {};
    int l = tid & 63, w = tid >> 6;
    int wm = (w >> 1) * 64, wn = (w & 1) * 64;

    for (int kt = 0; kt < K; kt += 64) {
#pragma unroll
        for (int i = 0; i < 4; i++)
            gload_lds16(arow[i] + kt + kc, &Als[i * 2048 + tid * 8]);
#pragma unroll
        for (int i = 0; i < 4; i++)
            gload_lds16(W + (size_t)(n0 + i * 32 + (tid >> 3)) * K + kt + kc,
                        &Bls[i * 2048 + tid * 8]);
        __syncthreads();
#pragma unroll
        for (int kk = 0; kk < 2; kk++) {
            int ko = kk * 32 + (l >> 4) * 8;
            bf16x8 af[4], bfr[4];
#pragma unroll
            for (int mi = 0; mi < 4; mi++)
                af[mi] = *(const bf16x8*)&Als[(wm + mi * 16 + (l & 15)) * 64 + ko];
#pragma unroll
            for (int ni = 0; ni < 4; ni++)
                bfr[ni] = *(const bf16x8*)&Bls[(wn + ni * 16 + (l & 15)) * 64 + ko];
#pragma unroll
            for (int mi = 0; mi < 4; mi++)
#pragma unroll
                for (int ni = 0; ni < 4; ni++)
                    acc[mi][ni] = mfma16(af[mi], bfr[ni], acc[mi][ni]);
        }
        __syncthreads();
    }
#pragma unroll
    for (int ni = 0; ni < 4; ni++) {
        int col = n0 + wn + ni * 16 + (l & 15);
        float bv = bias[col];
#pragma unroll
        for (int mi = 0; mi < 4; mi++) {
            int row0 = m0 + wm + mi * 16 + (l >> 4) * 4;
#pragma unroll
            for (int j = 0; j < 4; j++)
                C[(size_t)(row0 + j) * N + col] = f2bf(acc[mi][ni][j] + bv);
        }
    }
}

// ---------------- producer: xW GEMM tiles in t-slice order, coherent C stores ----------
// Writes C through an LDS tile then coalesced 8B AGENT-atomic stores (data visible
// at the IC); __syncthreads drains, then one slice-counter increment per tile.
template<int MODE>
DEV void produce(char* smem, int pid, int nprod, int nslices, int tps,
                 const short* Abase, const short* A2,
                 const int* tok0, const int* tok1,
                 const short* W, const float* bias, short* C,
                 int N, int K, unsigned* slice_cnt)
{
    short* Als = (short*)smem;               // 16 KB
    short* Bls = (short*)(smem + 16384);     // 16 KB
    short* Ct  = (short*)(smem + 32768);     // 32 KB
    int tid = threadIdx.x;
    int l = tid & 63, w = tid >> 6;
    int wm = (w >> 1) * 64, wn = (w & 1) * 64;
    int kc = (tid & 7) * 8;
    int ntile = nslices * tps;

    for (int q = pid; q < ntile; q += nprod) {
        int slice = q / tps, j = q % tps;
        int m0 = (MODE == M_XW1) ? (slice * 2 + (j >= 12 ? 1 : 0)) * 128 : slice * 128;
        int n0 = (MODE == M_XW1) ? (j % 12) * 128 : j * 128;

        const short* arow[4];
#pragma unroll
        for (int i = 0; i < 4; i++) {
            int gm = m0 + i * 32 + (tid >> 3);
            if (MODE == M_XW1) {
                int t = gm >> 8, s = gm & 255;
                int tok = (s < 128) ? tok0[s * 256 + t] : tok1[(s - 128) * 256 + t];
                arow[i] = Abase + (size_t)tok * 512;
            } else {
                arow[i] = Abase + (size_t)gm * 512;
            }
        }

        f32x4 acc[4][4] = {};
        for (int kt = 0; kt < K; kt += 64) {
#pragma unroll
            for (int i = 0; i < 4; i++) {
                const short* asrc;
                if (MODE == M_XW2) {
                    int gm = m0 + i * 32 + (tid >> 3);
                    const short* base = (kt < 512) ? Abase : A2;
                    asrc = base + (size_t)gm * 512 + (kt & 511) + kc;
                } else {
                    asrc = arow[i] + kt + kc;
                }
                gload_lds16(asrc, Als + i * 2048 + tid * 8);
            }
#pragma unroll
            for (int i = 0; i < 4; i++)
                gload_lds16(W + (size_t)(n0 + i * 32 + (tid >> 3)) * K + kt + kc,
                            Bls + i * 2048 + tid * 8);
            __syncthreads();
#pragma unroll
            for (int kk = 0; kk < 2; kk++) {
                int ko = kk * 32 + (l >> 4) * 8;
                bf16x8 af[4], bfr[4];
#pragma unroll
                for (int mi = 0; mi < 4; mi++)
                    af[mi] = *(const bf16x8*)&Als[(wm + mi * 16 + (l & 15)) * 64 + ko];
#pragma unroll
                for (int ni = 0; ni < 4; ni++)
                    bfr[ni] = *(const bf16x8*)&Bls[(wn + ni * 16 + (l & 15)) * 64 + ko];
#pragma unroll
                for (int mi = 0; mi < 4; mi++)
#pragma unroll
                    for (int ni = 0; ni < 4; ni++)
                        acc[mi][ni] = mfma16(af[mi], bfr[ni], acc[mi][ni]);
            }
            __syncthreads();
        }
        // epilogue -> LDS tile
#pragma unroll
        for (int ni = 0; ni < 4; ni++) {
            float bv = bias[n0 + wn + ni * 16 + (l & 15)];
#pragma unroll
            for (int mi = 0; mi < 4; mi++)
#pragma unroll
                for (int jj = 0; jj < 4; jj++)
                    Ct[(wm + mi * 16 + (l >> 4) * 4 + jj) * 128 + wn + ni * 16 + (l & 15)] =
                        f2bf(acc[mi][ni][jj] + bv);
        }
        __syncthreads();
        // coalesced coherent store: 4096 8B chunks, 16 rounds
        for (int r = 0; r < 16; r++) {
            int idx = r * 256 + tid;
            int row = idx >> 5, cc = idx & 31;
            unsigned long long val = *(const unsigned long long*)(Ct + row * 128 + cc * 4);
            __hip_atomic_store((unsigned long long*)(C + (size_t)(m0 + row) * N + n0 + cc * 4),
                               val, __ATOMIC_RELAXED, __HIP_MEMORY_SCOPE_AGENT);
        }
        __syncthreads();   // drain all threads' coherent stores before publish
        if (tid == 0)
            __hip_atomic_fetch_add(&slice_cnt[slice], 1u,
                                   __ATOMIC_RELAXED, __HIP_MEMORY_SCOPE_AGENT);
    }
}

// ---------------- fused GRU scan + xW producer ----------------
// bid < NSCAN: scan wg (cb = bid&15, rg = bid>>4), v10 structure:
//   LDS-resident Wh, coalesced coherent slab exchange via LDS, done-word sync,
//   register own-h. Gates step t additionally on slice_cnt[t] >= tps.
// bid >= NSCAN: producer wg computing xW tiles in slice order.
template<int WRITE_ALL, int MODE>
__global__ __launch_bounds__(256, 1) void gru_fused(
    const short* xW, const short* __restrict__ Wp, const float* __restrict__ bh,
    short* __restrict__ hb0, short* __restrict__ hb1,
    short* __restrict__ h_all, float* __restrict__ h_final,
    unsigned* __restrict__ done, unsigned* __restrict__ slice_cnt,
    const short* __restrict__ Abase, const short* __restrict__ A2,
    const int* __restrict__ tok0, const int* __restrict__ tok1,
    const short* __restrict__ W, const float* __restrict__ bias, short* C,
    int S, int T, int NSCAN, int nprod, int tps, int N, int K)
{
    __shared__ char smem[133376];
    int bid = blockIdx.x;
    int tid = threadIdx.x;

    if (bid >= NSCAN) {
        produce<MODE>(smem, bid - NSCAN, nprod, T, tps,
                      Abase, A2, tok0, tok1, W, bias, C, N, K, slice_cnt);
        return;
    }

    char* wl = smem;               // 96 KB Wh fragments
    char* sl = smem + 98304;       // 32 KB h slab, XOR-swizzled
    char* ho = smem + 131072;      // 32 x 72B out tile (padded rows)

    int cb = bid & 15, rg = bid >> 4;
    int r0 = rg * 32;
    int w = tid >> 6, l = tid & 63;
    int rt = w >> 1, ct = w & 1;
    int lrow = l & 15, lq = l >> 4;
    int colg = cb * 32 + ct * 16 + lrow;
    unsigned* mydone = done + rg * 32;

    // stage Wh slice once
    for (int rr = 0; rr < 24; rr++) {
        int flat = rr * 256 + tid;
        int lane = flat & 63, kk = (flat >> 6) & 15, lg = flat >> 10;
        int g = lg >> 1, c2 = lg & 1;
        gload_lds16(Wp + (((size_t)(g * 32 + cb * 2 + c2) * 16 + kk) * 64 + lane) * 8,
                    wl + flat * 16);
    }
    float bhv[3];
#pragma unroll
    for (int g = 0; g < 3; g++) bhv[g] = bh[g * 512 + colg];
    __syncthreads();   // drains Wh DMA

    float hp[4] = {};

    for (int t = 0; t < T; t++) {
        // gate: peers done with t-1 h (tid 0..15) AND xW slice t produced (tid 16)
        if (tid < 16) {
            if (t > 0)
                while (ald(&mydone[tid]) < (unsigned)t) __builtin_amdgcn_s_sleep(1);
        } else if (tid == 16) {
            while (ald(&slice_cnt[t]) < (unsigned)tps) __builtin_amdgcn_s_sleep(1);
        }
        __syncthreads();

        // xW loads (post-gate); latency hidden under slab load + MFMA
        short xrv[4], xzv[4], xnv[4];
        const short* xbase = xW + ((size_t)t * S + r0) * 1536 + colg;
#pragma unroll
        for (int j = 0; j < 4; j++) {
            const short* xp = xbase + (size_t)(rt * 16 + lq * 4 + j) * 1536;
            xrv[j] = xp[0]; xzv[j] = xp[512]; xnv[j] = xp[1024];
        }

        f32x4 acc[3] = {};
        if (t > 0) {
            const short* hprev = ((t & 1) ? hb0 : hb1) + (size_t)r0 * 512;
            // cooperative coalesced coherent slab load (32 KB)
            unsigned long long v[16];
            const unsigned long long* sp = (const unsigned long long*)hprev;
#pragma unroll
            for (int k = 0; k < 16; k++)
                v[k] = __hip_atomic_load(sp + k * 256 + tid,
                                         __ATOMIC_RELAXED, __HIP_MEMORY_SCOPE_AGENT);
#pragma unroll
            for (int k = 0; k < 16; k++) {
                int off = (k * 256 + tid) * 8;
                int row = off >> 10, colb = off & 1023;
                *(unsigned long long*)(sl + row * 1024 + (colb ^ ((row & 7) << 4))) = v[k];
            }
            __syncthreads();
            // A fragments from swizzled LDS slab
            bf16x8 afr[16];
            int ar = rt * 16 + lrow;
#pragma unroll
            for (int kk = 0; kk < 16; kk++) {
                int colb = kk * 64 + lq * 16;
                afr[kk] = *(const bf16x8*)(sl + ar * 1024 + (colb ^ ((ar & 7) << 4)));
            }
            // MFMA: 3 gates x 16 kk
#pragma unroll
            for (int g = 0; g < 3; g++) {
                const char* bbase = wl + (size_t)((g * 2 + ct) * 16) * 1024 + l * 16;
#pragma unroll
                for (int kk = 0; kk < 16; kk++) {
                    bf16x8 bfr = *(const bf16x8*)(bbase + kk * 1024);
                    acc[g] = mfma16(afr[kk], bfr, acc[g]);
                }
            }
        }

        // gates -> padded LDS out tile (72B rows: no bank aliasing across lq groups)
        float hv[4];
#pragma unroll
        for (int j = 0; j < 4; j++) {
            float r = sigmoidf_(bf2f(xrv[j]) + bhv[0] + acc[0][j]);
            float z = sigmoidf_(bf2f(xzv[j]) + bhv[1] + acc[1][j]);
            float n = tanhf_(bf2f(xnv[j]) + r * (acc[2][j] + bhv[2]));
            hv[j] = (1.f - z) * n + z * hp[j];
            hp[j] = hv[j];
            *(short*)(ho + (rt * 16 + lq * 4 + j) * 72 + (ct * 16 + lrow) * 2) = f2bf(hv[j]);
        }
        __syncthreads();   // out tile complete; slab reads done before next overwrite
        {
            int row = tid >> 3, ch = tid & 7;
            unsigned long long val = *(const unsigned long long*)(ho + row * 72 + ch * 8);
            short* hnew = (t & 1) ? hb1 : hb0;
            __hip_atomic_store(
                (unsigned long long*)(hnew + (size_t)(r0 + row) * 512 + cb * 32 + ch * 4),
                val, __ATOMIC_RELAXED, __HIP_MEMORY_SCOPE_AGENT);
            if (WRITE_ALL)
                *(unsigned long long*)(h_all + ((size_t)t * S + r0 + row) * 512 + cb * 32 + ch * 4) = val;
        }
        if (!WRITE_ALL && t == T - 1) {
#pragma unroll
            for (int j = 0; j < 4; j++)
                h_final[(size_t)(r0 + rt * 16 + lq * 4 + j) * 512 + colg] = hv[j];
        }
        __syncthreads();   // drain coherent stores before publish
        if (tid == 0)
            __hip_atomic_store(&mydone[cb], (unsigned)(t + 1),
                               __ATOMIC_RELAXED, __HIP_MEMORY_SCOPE_AGENT);
    }
}

// ---------------- per-(b) sums: u_all_sum ----------------
__global__ void embed_sum_k(const short* __restrict__ ebf, const int* __restrict__ tok,
                            float* __restrict__ out) {
    int b = blockIdx.x, d = threadIdx.x;
    float a0 = 0.f, a1 = 0.f;
    for (int t = 0; t < 256; t++) {
        const short* row = ebf + (size_t)tok[b * 256 + t] * 512;
        a0 += bf2f(row[d]); a1 += bf2f(row[d + 256]);
    }
    out[b * 512 + d] = a0; out[b * 512 + d + 256] = a1;
}
__global__ void hall_sum_k(const short* __restrict__ h_all, float* __restrict__ out) {
    int b = blockIdx.x, d = threadIdx.x;
    float a0 = 0.f, a1 = 0.f;
    for (int t = 0; t < 256; t++) {
        const short* row = h_all + ((size_t)t * 256 + b) * 512;
        a0 += bf2f(row[d]); a1 += bf2f(row[d + 256]);
    }
    out[b * 512 + d] = a0; out[b * 512 + d + 256] = a1;
}

// ---------------- dual attention combine (one wave per (t,b)) ----------------
template<int WORD>
__global__ __launch_bounds__(256) void attn_combine(
    const short* __restrict__ uA, const short* __restrict__ rsrc,
    const int* __restrict__ rtok, const float* __restrict__ usum,
    const float* __restrict__ Wv, short* __restrict__ ctx)
{
    int l = threadIdx.x & 63, w = threadIdx.x >> 6;
    int m = blockIdx.x * 4 + w;
    int t = m >> 7, b = m & 127;
    const short* rrow;
    if (WORD) rrow = rsrc + (size_t)rtok[b * 256 + t] * 512;
    else      rrow = rsrc + ((size_t)t * 256 + 128 + b) * 512;
    const short* urow = uA + (size_t)m * 512;
    int d0 = l * 8;
    short ru[8], uu[8];
    *(int4*)ru = *(const int4*)(rrow + d0);
    *(int4*)uu = *(const int4*)(urow + d0);
    float rv[8], dot = 0.f;
#pragma unroll
    for (int i = 0; i < 8; i++) { rv[i] = bf2f(ru[i]); dot += rv[i] * bf2f(uu[i]); }
#pragma unroll
    for (int off = 32; off >= 1; off >>= 1) dot += __shfl_xor(dot, off);
    float tw = tanhf_(dot);
    float e[8], se = 0.f;
#pragma unroll
    for (int i = 0; i < 8; i++) { e[i] = __expf(tw * Wv[d0 + i]); se += e[i]; }
#pragma unroll
    for (int off = 32; off >= 1; off >>= 1) se += __shfl_xor(se, off);
    float inv = 1.f / se;
    short ov[8];
#pragma unroll
    for (int i = 0; i < 8; i++) ov[i] = f2bf(e[i] * inv * usum[b * 512 + d0 + i] * rv[i]);
    *(int4*)(ctx + (size_t)m * 512 + d0) = *(int4*)ov;
}

// ---------------- final classifier + softmax ----------------
__global__ void final_head_k(const float* __restrict__ h2, const float* __restrict__ Wf,
                             const float* __restrict__ bfv, float* __restrict__ out) {
    int b = blockIdx.x, l = threadIdx.x;  // 64 threads
    float d0 = 0.f, d1 = 0.f;
    for (int k = l; k < 512; k += 64) {
        float h = h2[b * 512 + k];
        d0 += h * Wf[k];
        d1 += h * Wf[512 + k];
    }
#pragma unroll
    for (int off = 32; off >= 1; off >>= 1) { d0 += __shfl_xor(d0, off); d1 += __shfl_xor(d1, off); }
    if (l == 0) {
        float l0 = d0 + bfv[0], l1 = d1 + bfv[1];
        float mx = fmaxf(l0, l1);
        float e0 = __expf(l0 - mx), e1 = __expf(l1 - mx);
        float s = e0 + e1;
        out[b * 2] = e0 / s; out[b * 2 + 1] = e1 / s;
    }
}

extern "C" void kernel_launch(void* const* d_in, const int* in_sizes, int n_in,
                              void* d_out, int out_size, void* d_ws, size_t ws_size,
                              hipStream_t stream)
{
    const int* ask    = (const int*)d_in[0];
    const int* answer = (const int*)d_in[1];
    const int* askkw  = (const int*)d_in[2];
    const int* anskw  = (const int*)d_in[3];
    const float* embed = (const float*)d_in[4];
    const float* Wi1 = (const float*)d_in[5];
    const float* Wh1 = (const float*)d_in[6];
    const float* bi1 = (const float*)d_in[7];
    const float* bh1 = (const float*)d_in[8];
    const float* Aw  = (const float*)d_in[9];
    const float* bw  = (const float*)d_in[10];
    const float* Ww  = (const float*)d_in[11];
    const float* As  = (const float*)d_in[12];
    const float* bs  = (const float*)d_in[13];
    const float* Ws  = (const float*)d_in[14];
    const float* Wi2 = (const float*)d_in[15];
    const float* Wh2 = (const float*)d_in[16];
    const float* bi2 = (const float*)d_in[17];
    const float* bh2 = (const float*)d_in[18];
    const float* Wf  = (const float*)d_in[19];
    const float* bfv = (const float*)d_in[20];

    char* ws = (char*)d_ws;
    size_t off = 0;
    auto alloc = [&](size_t bytes) -> void* {
        void* p = (void*)(ws + off);
        off += (bytes + 255) & ~(size_t)255;
        return p;
    };
    short* embed_bf = (short*)alloc(50000ULL * 512 * 2);
    short* Wi1b = (short*)alloc(1536 * 512 * 2);
    short* Wp1  = (short*)alloc(1536 * 512 * 2);   // packed Wh1 fragments
    short* Awb  = (short*)alloc(512 * 512 * 2);
    short* Asb  = (short*)alloc(512 * 512 * 2);
    short* Wi2b = (short*)alloc(1536 * 1024 * 2);
    short* Wp2  = (short*)alloc(1536 * 512 * 2);   // packed Wh2 fragments
    char* X = (char*)alloc(201326592ULL);            // xW1 region, reused after GRU1
    short* xW1  = (short*)X;                         // [256][256][1536] bf16
    short* uA   = (short*)X;                         // [32768][512] bf16 (after GRU1)
    short* ctxW = (short*)(X + 33554432);            // [256][128][512] bf16
    short* ctxS = (short*)(X + 67108864);            // [256][128][512] bf16
    short* xW2  = (short*)(X + 100663296);           // [256][128][1536] bf16
    short* h_all = (short*)alloc(256ULL * 256 * 512 * 2);  // [t][s][512] bf16
    short* hb0 = (short*)alloc(256 * 512 * 2);
    short* hb1 = (short*)alloc(256 * 512 * 2);
    float* usumW = (float*)alloc(128 * 512 * 4);
    float* usumS = (float*)alloc(128 * 512 * 4);
    float* h2f   = (float*)alloc(128 * 512 * 4);
    unsigned* done1 = (unsigned*)alloc(8 * 32 * 4);  // GRU1: 8 rgs x 16 done words
    unsigned* done2 = (unsigned*)alloc(4 * 32 * 4);  // GRU2: 4 rgs
    unsigned* slc1  = (unsigned*)alloc(256 * 4);     // xW1 per-slice tile counters
    unsigned* slc2  = (unsigned*)alloc(256 * 4);     // xW2 per-slice tile counters

    if (off > ws_size) {
        fprintf(stderr, "kernel_launch: workspace too small: need %zu have %zu\n", off, ws_size);
        return;
    }

    // zero sync state (in-graph, every replay)
    hipMemsetAsync(done1, 0, 8 * 32 * 4, stream);
    hipMemsetAsync(done2, 0, 4 * 32 * 4, stream);
    hipMemsetAsync(slc1, 0, 256 * 4, stream);
    hipMemsetAsync(slc2, 0, 256 * 4, stream);

    auto cv = [&](const float* src, short* dst, int n) {
        int n4 = n / 4;
        f2bf_vec<<<(n4 + 255) / 256, 256, 0, stream>>>(src, dst, n4);
    };
    cv(embed, embed_bf, 50000 * 512);
    cv(Wi1, Wi1b, 1536 * 512);
    cv(Aw, Awb, 512 * 512);
    cv(As, Asb, 512 * 512);
    cv(Wi2, Wi2b, 1536 * 1024);
    pack_wh<<<dim3(96, 16), 64, 0, stream>>>(Wh1, Wp1);
    pack_wh<<<dim3(96, 16), 64, 0, stream>>>(Wh2, Wp2);

    // GRU1 fused with xW1 producers: 128 scan wgs + 128 producers
    {
        const short* xWa = xW1; const short* Wpa = Wp1; const float* bha = bh1;
        short* a0 = hb0; short* a1 = hb1; short* ha = h_all; float* hf = h2f;
        unsigned* dp = done1; unsigned* sc = slc1;
        const short* Ab = embed_bf; const short* A2p = nullptr;
        const int* t0 = ask; const int* t1 = answer;
        const short* Wm = Wi1b; const float* bi = bi1; short* Cp = xW1;
        int S = 256, T = 256, NSCAN = 128, nprod = 128, tps = 24, N = 1536, K = 512;
        void* args[] = { (void*)&xWa, (void*)&Wpa, (void*)&bha, (void*)&a0, (void*)&a1,
                         (void*)&ha, (void*)&hf, (void*)&dp, (void*)&sc,
                         (void*)&Ab, (void*)&A2p, (void*)&t0, (void*)&t1,
                         (void*)&Wm, (void*)&bi, (void*)&Cp,
                         (void*)&S, (void*)&T, (void*)&NSCAN, (void*)&nprod,
                         (void*)&tps, (void*)&N, (void*)&K };
        hipError_t e = hipLaunchCooperativeKernel(
            reinterpret_cast<void*>(&gru_fused<1, M_XW1>), dim3(256), dim3(256), args, 0, stream);
        if (e != hipSuccess)
            gru_fused<1, M_XW1><<<256, 256, 0, stream>>>(
                xWa, Wpa, bha, a0, a1, ha, hf, dp, sc, Ab, A2p, t0, t1, Wm, bi, Cp,
                S, T, NSCAN, nprod, tps, N, K);
    }

    // word attention
    embed_sum_k<<<128, 256, 0, stream>>>(embed_bf, askkw, usumW);
    gemm_bt<M_UAW><<<dim3(4, 256), 256, 0, stream>>>(
        embed_bf, nullptr, askkw, nullptr, Awb, bw, uA, 32768, 512, 512);
    attn_combine<1><<<8192, 256, 0, stream>>>(uA, embed_bf, anskw, usumW, Ww, ctxW);

    // seq attention
    hall_sum_k<<<128, 256, 0, stream>>>(h_all, usumS);
    gemm_bt<M_UAS><<<dim3(4, 256), 256, 0, stream>>>(
        h_all, nullptr, nullptr, nullptr, Asb, bs, uA, 32768, 512, 512);
    attn_combine<0><<<8192, 256, 0, stream>>>(uA, h_all, nullptr, usumS, Ws, ctxS);

    // GRU2 fused with xW2 producers: 64 scan wgs + 192 producers
    {
        const short* xWa = xW2; const short* Wpa = Wp2; const float* bha = bh2;
        short* a0 = hb0; short* a1 = hb1; short* ha = nullptr; float* hf = h2f;
        unsigned* dp = done2; unsigned* sc = slc2;
        const short* Ab = ctxW; const short* A2p = ctxS;
        const int* t0 = nullptr; const int* t1 = nullptr;
        const short* Wm = Wi2b; const float* bi = bi2; short* Cp = xW2;
        int S = 128, T = 256, NSCAN = 64, nprod = 192, tps = 12, N = 1536, K = 1024;
        void* args[] = { (void*)&xWa, (void*)&Wpa, (void*)&bha, (void*)&a0, (void*)&a1,
                         (void*)&ha, (void*)&hf, (void*)&dp, (void*)&sc,
                         (void*)&Ab, (void*)&A2p, (void*)&t0, (void*)&t1,
                         (void*)&Wm, (void*)&bi, (void*)&Cp,
                         (void*)&S, (void*)&T, (void*)&NSCAN, (void*)&nprod,
                         (void*)&tps, (void*)&N, (void*)&K };
        hipError_t e = hipLaunchCooperativeKernel(
            reinterpret_cast<void*>(&gru_fused<0, M_XW2>), dim3(256), dim3(256), args, 0, stream);
        if (e != hipSuccess)
            gru_fused<0, M_XW2><<<256, 256, 0, stream>>>(
                xWa, Wpa, bha, a0, a1, ha, hf, dp, sc, Ab, A2p, t0, t1, Wm, bi, Cp,
                S, T, NSCAN, nprod, tps, N, K);
    }

    final_head_k<<<128, 64, 0, stream>>>(h2f, Wf, bfv, (float*)d_out);
}

// Round 13
// 1926.719 us; speedup vs baseline: 1.7441x; 1.0263x over previous
//
#include <hip/hip_runtime.h>
#include <cstdio>

typedef __bf16 bf16x8 __attribute__((ext_vector_type(8)));
typedef float f32x4 __attribute__((ext_vector_type(4)));

#define DEV __device__ __forceinline__

DEV short f2bf(float f) {
    unsigned u = __builtin_bit_cast(unsigned, f);
    u += 0x7fffu + ((u >> 16) & 1u);   // RNE
    return (short)(u >> 16);
}
DEV float bf2f(short s) {
    unsigned u = ((unsigned)(unsigned short)s) << 16;
    return __builtin_bit_cast(float, u);
}
DEV float sigmoidf_(float x) { return 1.0f / (1.0f + __expf(-x)); }
DEV float tanhf_(float x) { float e = __expf(2.0f * x); return 1.0f - 2.0f / (e + 1.0f); }

DEV void gload_lds16(const void* g, void* l) {
    __builtin_amdgcn_global_load_lds(
        (__attribute__((address_space(1))) void*)(g),
        (__attribute__((address_space(3))) void*)(l), 16, 0, 0);
}
DEV f32x4 mfma16(bf16x8 a, bf16x8 b, f32x4 c) {
    return __builtin_amdgcn_mfma_f32_16x16x32_bf16(a, b, c, 0, 0, 0);
}
DEV unsigned ald(const unsigned* p) {
    return __hip_atomic_load(p, __ATOMIC_RELAXED, __HIP_MEMORY_SCOPE_AGENT);
}
DEV unsigned long long ald64(const void* p) {
    return __hip_atomic_load((const unsigned long long*)p, __ATOMIC_RELAXED, __HIP_MEMORY_SCOPE_AGENT);
}
DEV void ast64(void* p, unsigned long long v) {
    __hip_atomic_store((unsigned long long*)p, v, __ATOMIC_RELAXED, __HIP_MEMORY_SCOPE_AGENT);
}
DEV void ast32(void* p, unsigned v) {
    __hip_atomic_store((unsigned*)p, v, __ATOMIC_RELAXED, __HIP_MEMORY_SCOPE_AGENT);
}
DEV void aadd(unsigned* p, unsigned v) {
    __hip_atomic_fetch_add(p, v, __ATOMIC_RELAXED, __HIP_MEMORY_SCOPE_AGENT);
}

// ---------------- f32 -> bf16 convert ----------------
__global__ void f2bf_vec(const float* __restrict__ in, short* __restrict__ out, int n4) {
    int i = blockIdx.x * 256 + threadIdx.x;
    if (i >= n4) return;
    float4 v = reinterpret_cast<const float4*>(in)[i];
    short4 o;
    o.x = f2bf(v.x); o.y = f2bf(v.y); o.z = f2bf(v.z); o.w = f2bf(v.w);
    reinterpret_cast<short4*>(out)[i] = o;
}

// ---------------- pack Wh [1536][512] f32 into MFMA B-fragment order ----------------
__global__ void pack_wh(const float* __restrict__ Wh, short* __restrict__ Wp) {
    int tile = blockIdx.x, kk = blockIdx.y, l = threadIdx.x;  // 96 x 16, 64 thr
    int n = tile * 16 + (l & 15);
    int k0 = kk * 32 + (l >> 4) * 8;
    const float* src = Wh + (size_t)n * 512 + k0;
    short o[8];
#pragma unroll
    for (int e = 0; e < 8; e++) o[e] = f2bf(src[e]);
    *(int4*)(Wp + ((size_t)(tile * 16 + kk) * 64 + l) * 8) = *(int4*)o;
}

enum { A_XW1 = 0, A_UAW = 1, A_UAS = 2, A_XW2 = 3 };

// ---------------- generic 128x128 tile GEMM, coherent C via padded LDS tile ----------
// Ct stride 132 shorts (264B rows): kills the 8-way bank aliasing of 128-short rows.
template<int MODE>
DEV void gemm_tile(short* Als, short* Bls, short* Ct, int m0, int n0,
                   const short* Abase, const short* A2,
                   const int* tok0, const int* tok1,
                   const short* W, const float* bias, short* C, int N, int K)
{
    int tid = threadIdx.x;
    int l = tid & 63, w = tid >> 6;
    int wm = (w >> 1) * 64, wn = (w & 1) * 64;
    int kc = (tid & 7) * 8;

    const short* arow[4];
#pragma unroll
    for (int i = 0; i < 4; i++) {
        int gm = m0 + i * 32 + (tid >> 3);
        if (MODE == A_XW1) {
            int t = gm >> 8, s = gm & 255;
            int tok = (s < 128) ? tok0[s * 256 + t] : tok1[(s - 128) * 256 + t];
            arow[i] = Abase + (size_t)tok * 512;
        } else if (MODE == A_UAW) {
            int t = gm >> 7, b = gm & 127;
            arow[i] = Abase + (size_t)tok0[b * 256 + t] * 512;
        } else if (MODE == A_UAS) {
            int t = gm >> 7, b = gm & 127;
            arow[i] = Abase + ((size_t)t * 256 + b) * 512;
        } else {
            arow[i] = Abase + (size_t)gm * 512;
        }
    }

    f32x4 acc[4][4] = {};
    for (int kt = 0; kt < K; kt += 64) {
#pragma unroll
        for (int i = 0; i < 4; i++) {
            const short* asrc;
            if (MODE == A_XW2) {
                int gm = m0 + i * 32 + (tid >> 3);
                const short* base = (kt < 512) ? Abase : A2;
                asrc = base + (size_t)gm * 512 + (kt & 511) + kc;
            } else {
                asrc = arow[i] + kt + kc;
            }
            gload_lds16(asrc, Als + i * 2048 + tid * 8);
        }
#pragma unroll
        for (int i = 0; i < 4; i++)
            gload_lds16(W + (size_t)(n0 + i * 32 + (tid >> 3)) * K + kt + kc,
                        Bls + i * 2048 + tid * 8);
        __syncthreads();
#pragma unroll
        for (int kk = 0; kk < 2; kk++) {
            int ko = kk * 32 + (l >> 4) * 8;
            bf16x8 af[4], bfr[4];
#pragma unroll
            for (int mi = 0; mi < 4; mi++)
                af[mi] = *(const bf16x8*)&Als[(wm + mi * 16 + (l & 15)) * 64 + ko];
#pragma unroll
            for (int ni = 0; ni < 4; ni++)
                bfr[ni] = *(const bf16x8*)&Bls[(wn + ni * 16 + (l & 15)) * 64 + ko];
#pragma unroll
            for (int mi = 0; mi < 4; mi++)
#pragma unroll
                for (int ni = 0; ni < 4; ni++)
                    acc[mi][ni] = mfma16(af[mi], bfr[ni], acc[mi][ni]);
        }
        __syncthreads();
    }
#pragma unroll
    for (int ni = 0; ni < 4; ni++) {
        float bv = bias[n0 + wn + ni * 16 + (l & 15)];
#pragma unroll
        for (int mi = 0; mi < 4; mi++)
#pragma unroll
            for (int jj = 0; jj < 4; jj++)
                Ct[(wm + mi * 16 + (l >> 4) * 4 + jj) * 132 + wn + ni * 16 + (l & 15)] =
                    f2bf(acc[mi][ni][jj] + bv);
    }
    __syncthreads();
    for (int r = 0; r < 16; r++) {
        int idx = r * 256 + tid;
        int row = idx >> 5, cc = idx & 31;
        unsigned long long val = *(const unsigned long long*)(Ct + row * 132 + cc * 4);
        ast64(C + (size_t)(m0 + row) * N + n0 + cc * 4, val);
    }
    __syncthreads();   // all threads' coherent stores drained
}

// ---------------- attention building blocks (device) ----------------
DEV void embed_sum_dev(const short* ebf, const int* tok, float* out, int b) {
    int d = threadIdx.x;
    float a0 = 0.f, a1 = 0.f;
    for (int t = 0; t < 256; t++) {
        const short* row = ebf + (size_t)tok[b * 256 + t] * 512;
        a0 += bf2f(row[d]); a1 += bf2f(row[d + 256]);
    }
    ast32(&out[b * 512 + d], __builtin_bit_cast(unsigned, a0));
    ast32(&out[b * 512 + d + 256], __builtin_bit_cast(unsigned, a1));
}
DEV void hall_sum_dev(const short* h_all, float* out, int b) {
    int d = threadIdx.x;
    float a0 = 0.f, a1 = 0.f;
    for (int t = 0; t < 256; t++) {
        const short* row = h_all + ((size_t)t * 256 + b) * 512;
        a0 += bf2f(row[d]); a1 += bf2f(row[d + 256]);
    }
    ast32(&out[b * 512 + d], __builtin_bit_cast(unsigned, a0));
    ast32(&out[b * 512 + d + 256], __builtin_bit_cast(unsigned, a1));
}

// one block-equivalent of the original attn_combine (4 m's, wave w -> m = bb*4+w)
// uA/usum: atomic reads (in-kernel atomic-written); rsrc: plain (kernel-boundary data).
template<int WORD, int COHOUT>
DEV void combine4(int bb, const short* uA, const short* rsrc, const int* rtok,
                  const float* usum, const float* Wv, short* ctx)
{
    int l = threadIdx.x & 63, w = threadIdx.x >> 6;
    int m = bb * 4 + w;
    int t = m >> 7, b = m & 127;
    const short* rrow;
    if (WORD) rrow = rsrc + (size_t)rtok[b * 256 + t] * 512;
    else      rrow = rsrc + ((size_t)t * 256 + 128 + b) * 512;
    int d0 = l * 8;
    short ru[8], uu[8];
    *(int4*)ru = *(const int4*)(rrow + d0);
    *(unsigned long long*)uu       = ald64(uA + (size_t)m * 512 + d0);
    *((unsigned long long*)uu + 1) = ald64(uA + (size_t)m * 512 + d0 + 4);
    float rv[8], dot = 0.f;
#pragma unroll
    for (int i = 0; i < 8; i++) { rv[i] = bf2f(ru[i]); dot += rv[i] * bf2f(uu[i]); }
#pragma unroll
    for (int off = 32; off >= 1; off >>= 1) dot += __shfl_xor(dot, off);
    float tw = tanhf_(dot);
    float us[8];
#pragma unroll
    for (int i = 0; i < 4; i++) {
        unsigned long long uv = ald64(usum + b * 512 + d0 + i * 2);
        us[i * 2]     = __builtin_bit_cast(float, (unsigned)(uv & 0xffffffffu));
        us[i * 2 + 1] = __builtin_bit_cast(float, (unsigned)(uv >> 32));
    }
    float e[8], se = 0.f;
#pragma unroll
    for (int i = 0; i < 8; i++) { e[i] = __expf(tw * Wv[d0 + i]); se += e[i]; }
#pragma unroll
    for (int off = 32; off >= 1; off >>= 1) se += __shfl_xor(se, off);
    float inv = 1.f / se;
    short ov[8];
#pragma unroll
    for (int i = 0; i < 8; i++) ov[i] = f2bf(e[i] * inv * us[i] * rv[i]);
    if (COHOUT) {
        ast64(ctx + (size_t)m * 512 + d0,     *(unsigned long long*)ov);
        ast64(ctx + (size_t)m * 512 + d0 + 4, *((unsigned long long*)ov + 1));
    } else {
        *(int4*)(ctx + (size_t)m * 512 + d0) = *(int4*)ov;
    }
}

// ---------------- scan role (shared): v10/v11 structure, HW-proven sync ----------------
template<int WRITE_ALL>
DEV void scan_role(char* smem, int cb, int rg,
                   const short* xW, const short* Wp, const float* bh,
                   short* hb0, short* hb1, short* h_all, float* h_final,
                   unsigned* done, unsigned* slice_cnt, int tps, int S, int T)
{
    char* wl = smem;               // 96 KB Wh fragments
    char* sl = smem + 98304;       // 32 KB h slab, XOR-swizzled
    char* ho = smem + 131072;      // 32 x 72B out tile
    int tid = threadIdx.x;
    int r0 = rg * 32;
    int w = tid >> 6, l = tid & 63;
    int rt = w >> 1, ct = w & 1;
    int lrow = l & 15, lq = l >> 4;
    int colg = cb * 32 + ct * 16 + lrow;
    unsigned* mydone = done + rg * 32;

    for (int rr = 0; rr < 24; rr++) {
        int flat = rr * 256 + tid;
        int lane = flat & 63, kk = (flat >> 6) & 15, lg = flat >> 10;
        int g = lg >> 1, c2 = lg & 1;
        gload_lds16(Wp + (((size_t)(g * 32 + cb * 2 + c2) * 16 + kk) * 64 + lane) * 8,
                    wl + flat * 16);
    }
    float bhv[3];
#pragma unroll
    for (int g = 0; g < 3; g++) bhv[g] = bh[g * 512 + colg];
    __syncthreads();   // drains Wh DMA

    float hp[4] = {};

    for (int t = 0; t < T; t++) {
        if (tid < 16) {
            if (t > 0)
                while (ald(&mydone[tid]) < (unsigned)t) __builtin_amdgcn_s_sleep(1);
        } else if (tid == 16) {
            while (ald(&slice_cnt[t]) < (unsigned)tps) __builtin_amdgcn_s_sleep(1);
        }
        __syncthreads();

        short xrv[4], xzv[4], xnv[4];
        const short* xbase = xW + ((size_t)t * S + r0) * 1536 + colg;
#pragma unroll
        for (int j = 0; j < 4; j++) {
            const short* xp = xbase + (size_t)(rt * 16 + lq * 4 + j) * 1536;
            xrv[j] = xp[0]; xzv[j] = xp[512]; xnv[j] = xp[1024];
        }

        f32x4 acc[3] = {};
        if (t > 0) {
            const short* hprev = ((t & 1) ? hb0 : hb1) + (size_t)r0 * 512;
            unsigned long long v[16];
            const unsigned long long* sp = (const unsigned long long*)hprev;
#pragma unroll
            for (int k = 0; k < 16; k++)
                v[k] = ald64(sp + k * 256 + tid);
#pragma unroll
            for (int k = 0; k < 16; k++) {
                int off = (k * 256 + tid) * 8;
                int row = off >> 10, colb = off & 1023;
                *(unsigned long long*)(sl + row * 1024 + (colb ^ ((row & 7) << 4))) = v[k];
            }
            __syncthreads();
            bf16x8 afr[16];
            int ar = rt * 16 + lrow;
#pragma unroll
            for (int kk = 0; kk < 16; kk++) {
                int colb = kk * 64 + lq * 16;
                afr[kk] = *(const bf16x8*)(sl + ar * 1024 + (colb ^ ((ar & 7) << 4)));
            }
#pragma unroll
            for (int g = 0; g < 3; g++) {
                const char* bbase = wl + (size_t)((g * 2 + ct) * 16) * 1024 + l * 16;
#pragma unroll
                for (int kk = 0; kk < 16; kk++) {
                    bf16x8 bfr = *(const bf16x8*)(bbase + kk * 1024);
                    acc[g] = mfma16(afr[kk], bfr, acc[g]);
                }
            }
        }

        float hv[4];
#pragma unroll
        for (int j = 0; j < 4; j++) {
            float r = sigmoidf_(bf2f(xrv[j]) + bhv[0] + acc[0][j]);
            float z = sigmoidf_(bf2f(xzv[j]) + bhv[1] + acc[1][j]);
            float n = tanhf_(bf2f(xnv[j]) + r * (acc[2][j] + bhv[2]));
            hv[j] = (1.f - z) * n + z * hp[j];
            hp[j] = hv[j];
            *(short*)(ho + (rt * 16 + lq * 4 + j) * 72 + (ct * 16 + lrow) * 2) = f2bf(hv[j]);
        }
        __syncthreads();
        {
            int row = tid >> 3, ch = tid & 7;
            unsigned long long val = *(const unsigned long long*)(ho + row * 72 + ch * 8);
            short* hnew = (t & 1) ? hb1 : hb0;
            ast64(hnew + (size_t)(r0 + row) * 512 + cb * 32 + ch * 4, val);
            if (WRITE_ALL)
                *(unsigned long long*)(h_all + ((size_t)t * S + r0 + row) * 512 + cb * 32 + ch * 4) = val;
        }
        if (!WRITE_ALL && t == T - 1) {
#pragma unroll
            for (int j = 0; j < 4; j++)
                h_final[(size_t)(r0 + rt * 16 + lq * 4 + j) * 512 + colg] = hv[j];
        }
        __syncthreads();
        if (tid == 0)
            ast32(&mydone[cb], (unsigned)(t + 1));
    }
}

// ---------------- GRU1 fused: 128 scan + 128 producers (xW1 then word attention) -------
__global__ __launch_bounds__(256, 1) void gru_fused1(
    short* xW1, const short* __restrict__ Wp, const float* __restrict__ bh,
    short* __restrict__ hb0, short* __restrict__ hb1, short* __restrict__ h_all,
    unsigned* done, unsigned* slc,
    const short* __restrict__ embed_bf, const int* __restrict__ ask,
    const int* __restrict__ answer, const short* __restrict__ Wi1b,
    const float* __restrict__ bi1,
    const int* __restrict__ askkw, const int* __restrict__ anskw,
    const short* __restrict__ Awb, const float* __restrict__ bw,
    float* usumW, short* uAb, const float* __restrict__ Ww, short* ctxW,
    unsigned* wcnt)
{
    __shared__ char smem[133376];
    int bid = blockIdx.x, tid = threadIdx.x;

    if (bid >= 128) {
        int pid = bid - 128;
        short* Als = (short*)smem;
        short* Bls = (short*)(smem + 16384);
        short* Ct  = (short*)(smem + 32768);
        // xW1: 256 slices x 24 tiles, slice-ordered
        for (int q = pid; q < 256 * 24; q += 128) {
            int slice = q / 24, j = q % 24;
            int m0 = (slice * 2 + (j >= 12 ? 1 : 0)) * 128, n0 = (j % 12) * 128;
            gemm_tile<A_XW1>(Als, Bls, Ct, m0, n0, embed_bf, nullptr, ask, answer,
                             Wi1b, bi1, xW1, 1536, 512);
            if (tid == 0) aadd(&slc[slice], 1u);
        }
        // word attention (independent of GRU1; hidden under the scan)
        embed_sum_dev(embed_bf, askkw, usumW, pid);
        for (int k = 0; k < 8; k++) {
            int q = pid + k * 128;   // 1024 tiles of uA = ask_kw @ Aw^T + bw
            gemm_tile<A_UAW>(Als, Bls, Ct, (q >> 2) * 128, (q & 3) * 128,
                             embed_bf, nullptr, askkw, nullptr, Awb, bw, uAb, 512, 512);
        }
        if (tid == 0) {
            aadd(wcnt, 1u);
            while (ald(wcnt) < 128u) __builtin_amdgcn_s_sleep(1);
        }
        __syncthreads();
        for (int bb = pid * 64; bb < pid * 64 + 64; bb++)
            combine4<1, 0>(bb, uAb, embed_bf, anskw, usumW, Ww, ctxW);
        return;
    }
    scan_role<1>(smem, bid & 15, bid >> 4, xW1, Wp, bh, hb0, hb1, h_all, nullptr,
                 done, slc, 24, 256, 256);
}

// ---------------- GRU2 fused: seq-attention pre-phase (all 256) + 64 scan + 192 prod ----
__global__ __launch_bounds__(256, 1) void gru_fused2(
    short* xW2, const short* __restrict__ Wp, const float* __restrict__ bh,
    short* __restrict__ hb0, short* __restrict__ hb1, float* __restrict__ h_final,
    unsigned* done, unsigned* slc,
    const short* __restrict__ h_all, float* usumS, short* uAb,
    const short* __restrict__ Asb, const float* __restrict__ bs,
    const float* __restrict__ Ws, short* ctxS, const short* __restrict__ ctxW,
    const short* __restrict__ Wi2b, const float* __restrict__ bi2,
    unsigned* acnt, unsigned* ccnt)
{
    __shared__ char smem[133376];
    int bid = blockIdx.x, tid = threadIdx.x;
    short* Als = (short*)smem;
    short* Bls = (short*)(smem + 16384);
    short* Ct  = (short*)(smem + 32768);

    // pre-phase: seq attention on all 256 wgs
    if (bid < 128) hall_sum_dev(h_all, usumS, bid);
    for (int k = 0; k < 4; k++) {
        int q = bid + k * 256;   // 1024 tiles of uA = h_ask @ As^T + bs
        gemm_tile<A_UAS>(Als, Bls, Ct, (q >> 2) * 128, (q & 3) * 128,
                         h_all, nullptr, nullptr, nullptr, Asb, bs, uAb, 512, 512);
    }
    if (tid == 0) {
        aadd(acnt, 1u);
        while (ald(acnt) < 256u) __builtin_amdgcn_s_sleep(1);
    }
    __syncthreads();
    for (int bb = bid * 32; bb < bid * 32 + 32; bb++)
        combine4<0, 1>(bb, uAb, h_all, nullptr, usumS, Ws, ctxS);
    __syncthreads();                 // per-thread vmcnt(0): ctxS coherent stores drained
    if (tid == 0) aadd(ccnt, 1u);

    if (bid >= 64) {
        int pid = bid - 64;
        if (tid == 0) { while (ald(ccnt) < 256u) __builtin_amdgcn_s_sleep(1); }
        __syncthreads();
        for (int q = pid; q < 256 * 12; q += 192) {
            int slice = q / 12, j = q % 12;
            gemm_tile<A_XW2>(Als, Bls, Ct, slice * 128, j * 128,
                             ctxW, ctxS, nullptr, nullptr, Wi2b, bi2, xW2, 1536, 1024);
            if (tid == 0) aadd(&slc[slice], 1u);
        }
        return;
    }
    scan_role<0>(smem, bid & 15, bid >> 4, xW2, Wp, bh, hb0, hb1, nullptr, h_final,
                 done, slc, 12, 128, 256);
}

// ---------------- final classifier + softmax ----------------
__global__ void final_head_k(const float* __restrict__ h2, const float* __restrict__ Wf,
                             const float* __restrict__ bfv, float* __restrict__ out) {
    int b = blockIdx.x, l = threadIdx.x;  // 64 threads
    float d0 = 0.f, d1 = 0.f;
    for (int k = l; k < 512; k += 64) {
        float h = h2[b * 512 + k];
        d0 += h * Wf[k];
        d1 += h * Wf[512 + k];
    }
#pragma unroll
    for (int off = 32; off >= 1; off >>= 1) { d0 += __shfl_xor(d0, off); d1 += __shfl_xor(d1, off); }
    if (l == 0) {
        float l0 = d0 + bfv[0], l1 = d1 + bfv[1];
        float mx = fmaxf(l0, l1);
        float e0 = __expf(l0 - mx), e1 = __expf(l1 - mx);
        float s = e0 + e1;
        out[b * 2] = e0 / s; out[b * 2 + 1] = e1 / s;
    }
}

extern "C" void kernel_launch(void* const* d_in, const int* in_sizes, int n_in,
                              void* d_out, int out_size, void* d_ws, size_t ws_size,
                              hipStream_t stream)
{
    const int* ask    = (const int*)d_in[0];
    const int* answer = (const int*)d_in[1];
    const int* askkw  = (const int*)d_in[2];
    const int* anskw  = (const int*)d_in[3];
    const float* embed = (const float*)d_in[4];
    const float* Wi1 = (const float*)d_in[5];
    const float* Wh1 = (const float*)d_in[6];
    const float* bi1 = (const float*)d_in[7];
    const float* bh1 = (const float*)d_in[8];
    const float* Aw  = (const float*)d_in[9];
    const float* bw  = (const float*)d_in[10];
    const float* Ww  = (const float*)d_in[11];
    const float* As  = (const float*)d_in[12];
    const float* bs  = (const float*)d_in[13];
    const float* Ws  = (const float*)d_in[14];
    const float* Wi2 = (const float*)d_in[15];
    const float* Wh2 = (const float*)d_in[16];
    const float* bi2 = (const float*)d_in[17];
    const float* bh2 = (const float*)d_in[18];
    const float* Wf  = (const float*)d_in[19];
    const float* bfv = (const float*)d_in[20];

    char* ws = (char*)d_ws;
    size_t off = 0;
    auto alloc = [&](size_t bytes) -> void* {
        void* p = (void*)(ws + off);
        off += (bytes + 255) & ~(size_t)255;
        return p;
    };
    short* embed_bf = (short*)alloc(50000ULL * 512 * 2);
    short* Wi1b = (short*)alloc(1536 * 512 * 2);
    short* Wp1  = (short*)alloc(1536 * 512 * 2);
    short* Awb  = (short*)alloc(512 * 512 * 2);
    short* Asb  = (short*)alloc(512 * 512 * 2);
    short* Wi2b = (short*)alloc(1536 * 1024 * 2);
    short* Wp2  = (short*)alloc(1536 * 512 * 2);
    char* X = (char*)alloc(201326592ULL);            // xW1 [256][256][1536] bf16
    short* xW1  = (short*)X;
    short* xW2  = (short*)X;                         // [256][128][1536] bf16 (xW1 dead)
    short* ctxS = (short*)(X + 100663296);           // X tail: written in gru_fused2
                                                     // pre-phase, AFTER xW1 is dead and
                                                     // outside xW2's front 100.7 MB
    short* uAb  = (short*)alloc(32768ULL * 512 * 2); // uA (word attn, then seq attn)
    short* ctxW = (short*)alloc(32768ULL * 512 * 2); // live across both fused kernels
    short* h_all = (short*)alloc(256ULL * 256 * 512 * 2);
    short* hb0 = (short*)alloc(256 * 512 * 2);
    short* hb1 = (short*)alloc(256 * 512 * 2);
    float* usumW = (float*)alloc(128 * 512 * 4);
    float* usumS = (float*)alloc(128 * 512 * 4);
    float* h2f   = (float*)alloc(128 * 512 * 4);
    unsigned* syncb = (unsigned*)alloc((8 * 32 + 4 * 32 + 256 + 256 + 96) * 4);
    unsigned* done1 = syncb;
    unsigned* done2 = syncb + 8 * 32;
    unsigned* slc1  = syncb + 12 * 32;
    unsigned* slc2  = slc1 + 256;
    unsigned* wcnt1 = slc2 + 256;
    unsigned* acnt2 = wcnt1 + 32;
    unsigned* ccnt2 = wcnt1 + 64;

    if (off > ws_size) {
        fprintf(stderr, "kernel_launch: workspace too small: need %zu have %zu\n", off, ws_size);
        return;
    }

    hipMemsetAsync(syncb, 0, (8 * 32 + 4 * 32 + 256 + 256 + 96) * 4, stream);

    auto cv = [&](const float* src, short* dst, int n) {
        int n4 = n / 4;
        f2bf_vec<<<(n4 + 255) / 256, 256, 0, stream>>>(src, dst, n4);
    };
    cv(embed, embed_bf, 50000 * 512);
    cv(Wi1, Wi1b, 1536 * 512);
    cv(Aw, Awb, 512 * 512);
    cv(As, Asb, 512 * 512);
    cv(Wi2, Wi2b, 1536 * 1024);
    pack_wh<<<dim3(96, 16), 64, 0, stream>>>(Wh1, Wp1);
    pack_wh<<<dim3(96, 16), 64, 0, stream>>>(Wh2, Wp2);

    // GRU1 + xW1 producers + word attention
    {
        void* args[] = { (void*)&xW1, (void*)&Wp1, (void*)&bh1, (void*)&hb0, (void*)&hb1,
                         (void*)&h_all, (void*)&done1, (void*)&slc1,
                         (void*)&embed_bf, (void*)&ask, (void*)&answer, (void*)&Wi1b, (void*)&bi1,
                         (void*)&askkw, (void*)&anskw, (void*)&Awb, (void*)&bw,
                         (void*)&usumW, (void*)&uAb, (void*)&Ww, (void*)&ctxW, (void*)&wcnt1 };
        hipError_t e = hipLaunchCooperativeKernel(
            reinterpret_cast<void*>(&gru_fused1), dim3(256), dim3(256), args, 0, stream);
        if (e != hipSuccess)
            gru_fused1<<<256, 256, 0, stream>>>(
                xW1, Wp1, bh1, hb0, hb1, h_all, done1, slc1,
                embed_bf, ask, answer, Wi1b, bi1,
                askkw, anskw, Awb, bw, usumW, uAb, Ww, ctxW, wcnt1);
    }

    // GRU2 + seq-attention pre-phase + xW2 producers
    {
        void* args[] = { (void*)&xW2, (void*)&Wp2, (void*)&bh2, (void*)&hb0, (void*)&hb1,
                         (void*)&h2f, (void*)&done2, (void*)&slc2,
                         (void*)&h_all, (void*)&usumS, (void*)&uAb,
                         (void*)&Asb, (void*)&bs, (void*)&Ws, (void*)&ctxS, (void*)&ctxW,
                         (void*)&Wi2b, (void*)&bi2, (void*)&acnt2, (void*)&ccnt2 };
        hipError_t e = hipLaunchCooperativeKernel(
            reinterpret_cast<void*>(&gru_fused2), dim3(256), dim3(256), args, 0, stream);
        if (e != hipSuccess)
            gru_fused2<<<256, 256, 0, stream>>>(
                xW2, Wp2, bh2, hb0, hb1, h2f, done2, slc2,
                h_all, usumS, uAb, Asb, bs, Ws, ctxS, ctxW, Wi2b, bi2, acnt2, ccnt2);
    }

    final_head_k<<<128, 64, 0, stream>>>(h2f, Wf, bfv, (float*)d_out);
}